// Round 6
// baseline (230.274 us; speedup 1.0000x reference)
//
#include <hip/hip_runtime.h>
#include <hip/hip_bf16.h>
#include <stdint.h>

#define DIM_ 1024
#define NH_ 16
#define HD_ 64
#define B_ 4
#define S_ 2048
#define SC_ 1024
#define CD_ 768

typedef __attribute__((ext_vector_type(8))) short bf16x8;
typedef __attribute__((ext_vector_type(4))) short bf16x4;
typedef __attribute__((ext_vector_type(4))) float f32x4;

__device__ inline unsigned short f2bf(float f) {
    unsigned int u = __builtin_bit_cast(unsigned int, f);
    unsigned int r = (u + 0x7FFFu + ((u >> 16) & 1u)) >> 16;
    return (unsigned short)r;
}

#define GLOAD16(SRC, DST) __builtin_amdgcn_global_load_lds( \
    (const __attribute__((address_space(1))) void*)(SRC),   \
    (__attribute__((address_space(3))) void*)(DST), 16, 0, 0)

// ---------------- conversion kernels ----------------
__global__ void k_f32_to_bf16(const float* __restrict__ in, unsigned short* __restrict__ out, int n4) {
    int i = blockIdx.x * blockDim.x + threadIdx.x;
    int stride = gridDim.x * blockDim.x;
    for (; i < n4; i += stride) {
        float4 v = ((const float4*)in)[i];
        uint2 pk;
        pk.x = (unsigned int)f2bf(v.x) | ((unsigned int)f2bf(v.y) << 16);
        pk.y = (unsigned int)f2bf(v.z) | ((unsigned int)f2bf(v.w) << 16);
        ((uint2*)out)[i] = pk;
    }
}

// W is (K x 1024) -> WT (1024 x K) bf16. Lane handles 8 consecutive k for one n:
// reads coalesced across lanes (consecutive n), writes one 16B chunk.
__global__ void k_transposeW(const float* __restrict__ W, unsigned short* __restrict__ WT, int K) {
    int idx = blockIdx.x * blockDim.x + threadIdx.x;
    if (idx >= (K >> 3) * 1024) return;
    int n = idx & 1023;
    int k0 = (idx >> 10) << 3;
    unsigned int pk[4];
#pragma unroll
    for (int j = 0; j < 4; ++j) {
        unsigned short a = f2bf(W[(size_t)(k0 + 2 * j) * 1024 + n]);
        unsigned short b = f2bf(W[(size_t)(k0 + 2 * j + 1) * 1024 + n]);
        pk[j] = (unsigned int)a | ((unsigned int)b << 16);
    }
    *(uint4*)&WT[(size_t)n * K + k0] = *(uint4*)pk;
}

// per-batch key-padding bitmask (bit=1 -> masked); handles byte-bool or int32 upload
__global__ void k_mask_bits(const unsigned int* __restrict__ m, unsigned int* __restrict__ bits) {
    __shared__ int bm_s;
    if (threadIdx.x == 0) bm_s = 0;
    __syncthreads();
    int any = 0;
    for (int i = threadIdx.x; i < 1024; i += 256)
        if (m[i] > 1u) any = 1;
    if (any) atomicOr(&bm_s, 1);
    __syncthreads();
    const int boolmode = bm_s;
    const int w = threadIdx.x;
    if (w < 128) {
        const unsigned char* mb = (const unsigned char*)m;
        unsigned int out = 0;
        for (int j = 0; j < 32; ++j) {
            int c = w * 32 + j;
            int masked = boolmode ? (mb[c] != 0) : (m[c] != 0u);
            out |= (unsigned int)masked << j;
        }
        bits[w] = out;
    }
}

// ---------------- bf16 GEMM, B^T layout, global_load_lds staging (m97 pattern) ----------------
// C = (A * BT^T + bias) * oscale.  T1 XCD-swizzle (both grids have nwg%8==0; transpose
// of 8 x (nwg/8) is bijective).
template<int EPI>
__global__ __launch_bounds__(256) void k_gemm_bt(
    const unsigned short* __restrict__ A, const unsigned short* __restrict__ BT,
    const float* __restrict__ bias, float oscale,
    unsigned short* __restrict__ Cb, float* __restrict__ Cf,
    int M, int N, int K)
{
    __shared__ unsigned short As[128 * 32];
    __shared__ unsigned short Bs[128 * 32];
    const int t = threadIdx.x;
    const int w = t >> 6, lane = t & 63;
    const int lo = lane & 15, hi = lane >> 4;
    const int nwg = gridDim.x * gridDim.y;
    const int wg = blockIdx.y * gridDim.x + blockIdx.x;
    const int swz = (wg & 7) * (nwg >> 3) + (wg >> 3);
    const int m0 = (swz % gridDim.x) * 128, n0 = (swz / gridDim.x) * 128;
    const int wr = (w >> 1) * 64, wc = (w & 1) * 64;
    const int srow = lane >> 2;
    const int scol = (lane & 3) * 8;

    f32x4 zero4 = {0.f, 0.f, 0.f, 0.f};
    f32x4 acc[4][4];
    for (int i = 0; i < 4; ++i)
        for (int j = 0; j < 4; ++j) acc[i][j] = zero4;

    for (int k0 = 0; k0 < K; k0 += 32) {
#pragma unroll
        for (int p = 0; p < 2; ++p) {
            int chunk = w * 2 + p;
            int r = chunk * 16 + srow;
            GLOAD16(&A[(size_t)(m0 + r) * K + k0 + scol], &As[chunk * 512]);
            GLOAD16(&BT[(size_t)(n0 + r) * K + k0 + scol], &Bs[chunk * 512]);
        }
        __syncthreads();
        bf16x8 af[4], bfr[4];
#pragma unroll
        for (int i = 0; i < 4; ++i)
            af[i] = *(const bf16x8*)&As[(wr + i * 16 + lo) * 32 + (hi << 3)];
#pragma unroll
        for (int j = 0; j < 4; ++j)
            bfr[j] = *(const bf16x8*)&Bs[(wc + j * 16 + lo) * 32 + (hi << 3)];
#pragma unroll
        for (int i = 0; i < 4; ++i)
#pragma unroll
            for (int j = 0; j < 4; ++j)
                acc[i][j] = __builtin_amdgcn_mfma_f32_16x16x32_bf16(af[i], bfr[j], acc[i][j], 0, 0, 0);
        __syncthreads();
    }

#pragma unroll
    for (int i = 0; i < 4; ++i) {
#pragma unroll
        for (int j = 0; j < 4; ++j) {
#pragma unroll
            for (int r = 0; r < 4; ++r) {
                int m = m0 + wr + i * 16 + (hi << 2) + r;
                int n = n0 + wc + j * 16 + lo;
                float v = (acc[i][j][r] + bias[n]) * oscale;
                if (EPI == 0) {
                    Cb[(size_t)m * N + n] = f2bf(v);
                } else if (EPI == 1) {
                    int b = m >> 10, c = m & 1023;
                    Cb[(size_t)((b << 10) + n) * 1024 + c] = f2bf(v);
                } else {
                    Cf[(size_t)m * N + n] = v;
                }
            }
        }
    }
}

// ---------------- fused flash attention: LDS-staged K/V, swapped-QK^T, base-2 in-reg softmax ----------------
// Q pre-scaled by 0.125*log2(e) in its projection -> scores are log2-domain; exps are exp2f.
// Per-tile rescale (round-4-proven structure; defer-max reverted for bisect).
__global__ __launch_bounds__(256) void k_attn(
    const unsigned short* __restrict__ Q, const unsigned short* __restrict__ Kb,
    const unsigned short* __restrict__ VT, const unsigned int* __restrict__ bits,
    unsigned short* __restrict__ Ob)
{
    __shared__ unsigned short lds[16384];  // K0|K1|V0|V1, 4096 ushorts (64x64) each
    const int t = threadIdx.x, w = t >> 6, lane = t & 63;
    const int lo = lane & 15, hi = lane >> 4;
    const int qt = blockIdx.x, h = blockIdx.y, b = blockIdx.z;
    const int qr0 = qt * 128 + w * 32;
    const int l7 = lo & 7;

    const int srow = lane >> 3;                 // 0..7 within 8-row sub-pass
    const int scb  = ((lane & 7) ^ srow) << 3;  // pre-swizzled source 16B block

    bf16x8 qf[2][2];
#pragma unroll
    for (int qh = 0; qh < 2; ++qh)
#pragma unroll
        for (int kk = 0; kk < 2; ++kk)
            qf[qh][kk] = *(const bf16x8*)&Q[(size_t)(b * S_ + qr0 + qh * 16 + lo) * DIM_ + h * 64 + kk * 32 + hi * 8];

    f32x4 zero4 = {0.f, 0.f, 0.f, 0.f};
    float mrow[2] = {-1e30f, -1e30f}, lsum[2] = {0.f, 0.f};
    f32x4 o[4][2];
#pragma unroll
    for (int dt = 0; dt < 4; ++dt)
#pragma unroll
        for (int qh = 0; qh < 2; ++qh) o[dt][qh] = zero4;

    // prologue: stage tile 0 into buf 0
#pragma unroll
    for (int s = 0; s < 2; ++s) {
        int rl = w * 16 + s * 8 + srow;
        GLOAD16(&Kb[(size_t)(b * SC_ + rl) * DIM_ + h * 64 + scb], &lds[(w * 16 + s * 8) * 64]);
        GLOAD16(&VT[(size_t)(b * 1024 + h * 64 + rl) * SC_ + scb], &lds[8192 + (w * 16 + s * 8) * 64]);
    }
    __syncthreads();

    int cur = 0;
    for (int tt = 0; tt < 16; ++tt) {
        if (tt < 15) {  // stage next tile (drains at this iter's barrier)
            int c0n = (tt + 1) * 64;
#pragma unroll
            for (int s = 0; s < 2; ++s) {
                int rl = w * 16 + s * 8 + srow;
                GLOAD16(&Kb[(size_t)(b * SC_ + c0n + rl) * DIM_ + h * 64 + scb],
                        &lds[(cur ^ 1) * 4096 + (w * 16 + s * 8) * 64]);
                GLOAD16(&VT[(size_t)(b * 1024 + h * 64 + rl) * SC_ + c0n + scb],
                        &lds[8192 + (cur ^ 1) * 4096 + (w * 16 + s * 8) * 64]);
            }
        }
        const unsigned short* Kl = &lds[cur * 4096];
        const unsigned short* Vl = &lds[8192 + cur * 4096];

        // QK^T (swapped): st[n][qh] rows kv = n*16+hi*4+r, cols q = lo (half qh)
        f32x4 st[4][2];
#pragma unroll
        for (int n = 0; n < 4; ++n)
#pragma unroll
            for (int qh = 0; qh < 2; ++qh) st[n][qh] = zero4;
#pragma unroll
        for (int n = 0; n < 4; ++n) {
            const int R = n * 16 + lo;
            bf16x8 k0 = *(const bf16x8*)&Kl[R * 64 + ((hi ^ l7) << 3)];
            bf16x8 k1 = *(const bf16x8*)&Kl[R * 64 + (((4 + hi) ^ l7) << 3)];
#pragma unroll
            for (int qh = 0; qh < 2; ++qh) {
                st[n][qh] = __builtin_amdgcn_mfma_f32_16x16x32_bf16(k0, qf[qh][0], st[n][qh], 0, 0, 0);
                st[n][qh] = __builtin_amdgcn_mfma_f32_16x16x32_bf16(k1, qf[qh][1], st[n][qh], 0, 0, 0);
            }
        }
        // V^T fragments for K=16 PV
        bf16x4 vf[4][4];
#pragma unroll
        for (int dt = 0; dt < 4; ++dt)
#pragma unroll
            for (int n = 0; n < 4; ++n)
                vf[dt][n] = *(const bf16x4*)&Vl[(dt * 16 + lo) * 64
                              + (((2 * n + (hi >> 1)) ^ l7) << 3) + ((hi & 1) << 2)];

        uint2 mw = *(const uint2*)&bits[b * 32 + tt * 2];

        // mask (scores already log2-scaled) + lane-local max
        float p[2][4][4];
        float mx[2] = {-1e30f, -1e30f};
#pragma unroll
        for (int n = 0; n < 4; ++n) {
            unsigned int wd = (n & 2) ? mw.y : mw.x;
#pragma unroll
            for (int r = 0; r < 4; ++r) {
                int sh = ((n & 1) << 4) + (hi << 2) + r;
                bool mk = (wd >> sh) & 1u;
#pragma unroll
                for (int qh = 0; qh < 2; ++qh) {
                    float s = mk ? -1e30f : st[n][qh][r];
                    p[qh][n][r] = s;
                    mx[qh] = fmaxf(mx[qh], s);
                }
            }
        }
        // per-tile rescale (round-4 structure), base-2 domain
#pragma unroll
        for (int qh = 0; qh < 2; ++qh) {
            float m2 = fmaxf(mx[qh], __shfl_xor(mx[qh], 16));
            m2 = fmaxf(m2, __shfl_xor(m2, 32));
            float mnew = fmaxf(mrow[qh], m2);
            float scl = exp2f(mrow[qh] - mnew);
            mrow[qh] = mnew;
            float rs = 0.f;
#pragma unroll
            for (int n = 0; n < 4; ++n)
#pragma unroll
                for (int r = 0; r < 4; ++r) {
                    float e = exp2f(p[qh][n][r] - mnew);
                    p[qh][n][r] = e;
                    rs += e;
                }
            rs += __shfl_xor(rs, 16);
            rs += __shfl_xor(rs, 32);
            lsum[qh] = lsum[qh] * scl + rs;
#pragma unroll
            for (int dt = 0; dt < 4; ++dt)
#pragma unroll
                for (int r = 0; r < 4; ++r)
                    o[dt][qh][r] *= scl;
        }
        // pack P^T (manual RTNE, round-4-proven) and PV (K=16)
#pragma unroll
        for (int qh = 0; qh < 2; ++qh) {
#pragma unroll
            for (int n = 0; n < 4; ++n) {
                uint2 pk2;
                pk2.x = (unsigned int)f2bf(p[qh][n][0]) | ((unsigned int)f2bf(p[qh][n][1]) << 16);
                pk2.y = (unsigned int)f2bf(p[qh][n][2]) | ((unsigned int)f2bf(p[qh][n][3]) << 16);
                bf16x4 pb = __builtin_bit_cast(bf16x4, pk2);
#pragma unroll
                for (int dt = 0; dt < 4; ++dt)
                    o[dt][qh] = __builtin_amdgcn_mfma_f32_16x16x16bf16_1k(vf[dt][n], pb, o[dt][qh], 0, 0, 0);
            }
        }
        __syncthreads();  // drains stage vmcnt + all waves' LDS reads of buf[cur]
        cur ^= 1;
    }

    // epilogue: O^T -> O via wave-private LDS transpose
    unsigned short* Tl = &lds[w * 2304];  // [32][72]
    float inv[2] = {1.0f / lsum[0], 1.0f / lsum[1]};
#pragma unroll
    for (int qh = 0; qh < 2; ++qh)
#pragma unroll
        for (int dt = 0; dt < 4; ++dt)
#pragma unroll
            for (int r = 0; r < 4; ++r)
                Tl[(qh * 16 + lo) * 72 + dt * 16 + hi * 4 + r] = f2bf(o[dt][qh][r] * inv[qh]);
#pragma unroll
    for (int ps = 0; ps < 4; ++ps) {
        int row = ps * 8 + (lane >> 3);
        int col = (lane & 7) * 8;
        bf16x8 v = *(const bf16x8*)&Tl[row * 72 + col];
        *(bf16x8*)&Ob[(size_t)(b * S_ + qr0 + row) * DIM_ + h * 64 + col] = v;
    }
}

// ---------------- launch ----------------
extern "C" void kernel_launch(void* const* d_in, const int* in_sizes, int n_in,
                              void* d_out, int out_size, void* d_ws, size_t ws_size,
                              hipStream_t stream)
{
    const float* x  = (const float*)d_in[0];
    const float* cx = (const float*)d_in[1];
    const void* mask = d_in[2];
    const float* Wq = (const float*)d_in[3];
    const float* bq = (const float*)d_in[4];
    const float* Wk = (const float*)d_in[5];
    const float* bk = (const float*)d_in[6];
    const float* Wv = (const float*)d_in[7];
    const float* bv = (const float*)d_in[8];
    const float* Wo = (const float*)d_in[9];
    const float* bo = (const float*)d_in[10];

    unsigned short* ws = (unsigned short*)d_ws;
    const size_t XB  = 0;                                  // 8192*1024 (x bf16; later attn out)
    const size_t CXB = XB  + (size_t)8192 * 1024;          // 4096*768
    const size_t WQT = CXB + (size_t)4096 * 768;           // 1024*1024
    const size_t WKT = WQT + (size_t)1024 * 1024;          // 1024*768
    const size_t WVT = WKT + (size_t)1024 * 768;           // 1024*768
    const size_t WOT = WVT + (size_t)1024 * 768;           // 1024*1024
    const size_t QB  = WOT + (size_t)1024 * 1024;          // 8192*1024
    const size_t KB  = QB  + (size_t)8192 * 1024;          // 4096*1024
    const size_t VTB = KB  + (size_t)4096 * 1024;          // 4*1024*1024
    const size_t MBT = VTB + (size_t)4 * 1024 * 1024;      // 128 uint32

    k_f32_to_bf16<<<2048, 256, 0, stream>>>(x,  ws + XB,  8192 * 1024 / 4);
    k_f32_to_bf16<<<2048, 256, 0, stream>>>(cx, ws + CXB, 4096 * 768 / 4);
    k_transposeW<<<512, 256, 0, stream>>>(Wq, ws + WQT, 1024);
    k_transposeW<<<384, 256, 0, stream>>>(Wk, ws + WKT, 768);
    k_transposeW<<<384, 256, 0, stream>>>(Wv, ws + WVT, 768);
    k_transposeW<<<512, 256, 0, stream>>>(Wo, ws + WOT, 1024);
    unsigned int* mbits = (unsigned int*)(ws + MBT);
    k_mask_bits<<<1, 256, 0, stream>>>((const unsigned int*)mask, mbits);

    const float QSCALE = 0.125f * 1.44269504088896340736f;  // fold 1/sqrt(64) * log2(e) into Q
    dim3 gq(8192 / 128, 1024 / 128);
    dim3 gk(4096 / 128, 1024 / 128);
    k_gemm_bt<0><<<gq, 256, 0, stream>>>(ws + XB,  ws + WQT, bq, QSCALE, ws + QB, nullptr, 8192, 1024, 1024);
    k_gemm_bt<0><<<gk, 256, 0, stream>>>(ws + CXB, ws + WKT, bk, 1.0f, ws + KB, nullptr, 4096, 1024, 768);
    k_gemm_bt<1><<<gk, 256, 0, stream>>>(ws + CXB, ws + WVT, bv, 1.0f, ws + VTB, nullptr, 4096, 1024, 768);

    dim3 ga(S_ / 128, NH_, B_);
    k_attn<<<ga, 256, 0, stream>>>(ws + QB, ws + KB, ws + VTB, mbits, ws + XB);

    k_gemm_bt<2><<<gq, 256, 0, stream>>>(ws + XB, ws + WOT, bo, 1.0f, nullptr, (float*)d_out, 8192, 1024, 1024);
}

// Round 8
// 196.770 us; speedup vs baseline: 1.1703x; 1.1703x over previous
//
#include <hip/hip_runtime.h>
#include <hip/hip_bf16.h>
#include <stdint.h>

#define DIM_ 1024
#define NH_ 16
#define HD_ 64
#define B_ 4
#define S_ 2048
#define SC_ 1024
#define CD_ 768

typedef __attribute__((ext_vector_type(8))) short bf16x8;
typedef __attribute__((ext_vector_type(4))) short bf16x4;
typedef __attribute__((ext_vector_type(4))) float f32x4;

__device__ inline unsigned short f2bf(float f) {
    unsigned int u = __builtin_bit_cast(unsigned int, f);
    unsigned int r = (u + 0x7FFFu + ((u >> 16) & 1u)) >> 16;
    return (unsigned short)r;
}

#define GLOAD16(SRC, DST) __builtin_amdgcn_global_load_lds( \
    (const __attribute__((address_space(1))) void*)(SRC),   \
    (__attribute__((address_space(3))) void*)(DST), 16, 0, 0)

// ---------------- conversion kernels ----------------
__global__ void k_f32_to_bf16(const float* __restrict__ in, unsigned short* __restrict__ out, int n4) {
    int i = blockIdx.x * blockDim.x + threadIdx.x;
    int stride = gridDim.x * blockDim.x;
    for (; i < n4; i += stride) {
        float4 v = ((const float4*)in)[i];
        uint2 pk;
        pk.x = (unsigned int)f2bf(v.x) | ((unsigned int)f2bf(v.y) << 16);
        pk.y = (unsigned int)f2bf(v.z) | ((unsigned int)f2bf(v.w) << 16);
        ((uint2*)out)[i] = pk;
    }
}

// W is (K x 1024) -> WT (1024 x K) bf16; coalesced reads, 16B writes
__global__ void k_transposeW(const float* __restrict__ W, unsigned short* __restrict__ WT, int K) {
    int idx = blockIdx.x * blockDim.x + threadIdx.x;
    if (idx >= (K >> 3) * 1024) return;
    int n = idx & 1023;
    int k0 = (idx >> 10) << 3;
    unsigned int pk[4];
#pragma unroll
    for (int j = 0; j < 4; ++j) {
        unsigned short a = f2bf(W[(size_t)(k0 + 2 * j) * 1024 + n]);
        unsigned short b = f2bf(W[(size_t)(k0 + 2 * j + 1) * 1024 + n]);
        pk[j] = (unsigned int)a | ((unsigned int)b << 16);
    }
    *(uint4*)&WT[(size_t)n * K + k0] = *(uint4*)pk;
}

// per-batch key-padding bitmask (bit=1 -> masked) + nt[b] = (last tile with any
// valid key)+1. Handles byte-bool or int32 mask upload. Mask application in
// k_attn stays bit-identical to the proven R6 path.
__global__ void k_mask_bits(const unsigned int* __restrict__ m,
                            unsigned int* __restrict__ bits, int* __restrict__ ntp) {
    __shared__ int bm_s;
    __shared__ unsigned int wbits[128];
    if (threadIdx.x == 0) bm_s = 0;
    __syncthreads();
    int any = 0;
    for (int i = threadIdx.x; i < 1024; i += 256)  // first 4096 bytes: safe both modes
        if (m[i] > 1u) any = 1;
    if (any) atomicOr(&bm_s, 1);
    __syncthreads();
    const int boolmode = bm_s;
    const int w = threadIdx.x;
    if (w < 128) {
        const unsigned char* mb = (const unsigned char*)m;
        unsigned int out = 0;
        for (int j = 0; j < 32; ++j) {
            int c = w * 32 + j;
            int masked = boolmode ? (mb[c] != 0) : (m[c] != 0u);
            out |= (unsigned int)masked << j;
        }
        bits[w] = out;
        wbits[w] = out;
    }
    __syncthreads();
    if (threadIdx.x < 4) {
        int nt = 0;
        for (int tt = 0; tt < 16; ++tt) {
            unsigned int w0 = wbits[threadIdx.x * 32 + tt * 2];
            unsigned int w1 = wbits[threadIdx.x * 32 + tt * 2 + 1];
            if ((w0 & w1) != 0xFFFFFFFFu) nt = tt + 1;  // tile has >=1 valid key
        }
        ntp[threadIdx.x] = nt;
    }
}

// ---------------- bf16 GEMM, B^T layout, global_load_lds staging (m97 pattern) ----------------
// C = (A * BT^T + bias) * oscale.  T1 XCD-swizzle (all grids nwg%8==0).
// EPI 0: bf16 row-major (stride 1024). EPI 2: f32 row-major. EPI 3: merged K|V -
//   n<1024 -> K bf16 row-major into Cb (bias=bias); n>=1024 -> V^T (b,d,c) into
//   Cb2 (bias=bias2[n-1024]).
template<int EPI>
__global__ __launch_bounds__(256) void k_gemm_bt(
    const unsigned short* __restrict__ A, const unsigned short* __restrict__ BT,
    const float* __restrict__ bias, const float* __restrict__ bias2, float oscale,
    unsigned short* __restrict__ Cb, unsigned short* __restrict__ Cb2,
    float* __restrict__ Cf, int M, int N, int K)
{
    __shared__ unsigned short As[128 * 32];
    __shared__ unsigned short Bs[128 * 32];
    const int t = threadIdx.x;
    const int w = t >> 6, lane = t & 63;
    const int lo = lane & 15, hi = lane >> 4;
    const int nwg = gridDim.x * gridDim.y;
    const int wg = blockIdx.y * gridDim.x + blockIdx.x;
    const int swz = (wg & 7) * (nwg >> 3) + (wg >> 3);
    const int m0 = (swz % gridDim.x) * 128, n0 = (swz / gridDim.x) * 128;
    const int wr = (w >> 1) * 64, wc = (w & 1) * 64;
    const int srow = lane >> 2;
    const int scol = (lane & 3) * 8;

    f32x4 zero4 = {0.f, 0.f, 0.f, 0.f};
    f32x4 acc[4][4];
    for (int i = 0; i < 4; ++i)
        for (int j = 0; j < 4; ++j) acc[i][j] = zero4;

    for (int k0 = 0; k0 < K; k0 += 32) {
#pragma unroll
        for (int p = 0; p < 2; ++p) {
            int chunk = w * 2 + p;
            int r = chunk * 16 + srow;
            GLOAD16(&A[(size_t)(m0 + r) * K + k0 + scol], &As[chunk * 512]);
            GLOAD16(&BT[(size_t)(n0 + r) * K + k0 + scol], &Bs[chunk * 512]);
        }
        __syncthreads();
        bf16x8 af[4], bfr[4];
#pragma unroll
        for (int i = 0; i < 4; ++i)
            af[i] = *(const bf16x8*)&As[(wr + i * 16 + lo) * 32 + (hi << 3)];
#pragma unroll
        for (int j = 0; j < 4; ++j)
            bfr[j] = *(const bf16x8*)&Bs[(wc + j * 16 + lo) * 32 + (hi << 3)];
#pragma unroll
        for (int i = 0; i < 4; ++i)
#pragma unroll
            for (int j = 0; j < 4; ++j)
                acc[i][j] = __builtin_amdgcn_mfma_f32_16x16x32_bf16(af[i], bfr[j], acc[i][j], 0, 0, 0);
        __syncthreads();
    }

#pragma unroll
    for (int i = 0; i < 4; ++i) {
#pragma unroll
        for (int j = 0; j < 4; ++j) {
#pragma unroll
            for (int r = 0; r < 4; ++r) {
                int m = m0 + wr + i * 16 + (hi << 2) + r;
                int n = n0 + wc + j * 16 + lo;
                if (EPI == 0) {
                    float v = (acc[i][j][r] + bias[n]) * oscale;
                    Cb[(size_t)m * 1024 + n] = f2bf(v);
                } else if (EPI == 2) {
                    float v = (acc[i][j][r] + bias[n]) * oscale;
                    Cf[(size_t)m * 1024 + n] = v;
                } else if (EPI == 3) {
                    if (n < 1024) {
                        float v = acc[i][j][r] + bias[n];
                        Cb[(size_t)m * 1024 + n] = f2bf(v);
                    } else {
                        float v = acc[i][j][r] + bias2[n - 1024];
                        int bb = m >> 10, c = m & 1023;
                        Cb2[(size_t)((bb << 10) + (n - 1024)) * 1024 + c] = f2bf(v);
                    }
                }
            }
        }
    }
}

// ---------------- fused flash attention ----------------
// LDS-staged K/V (double-buffered, XOR-swizzled both sides), swapped-QK^T,
// base-2 in-register softmax (Q pre-scaled by 0.125*log2e). R6-identical mask
// semantics; fully-masked tail tiles skipped (exact no-ops); fully-valid tiles
// take a wave-uniform no-mask fast path.
__global__ __launch_bounds__(256) void k_attn(
    const unsigned short* __restrict__ Q, const unsigned short* __restrict__ Kb,
    const unsigned short* __restrict__ VT, const unsigned int* __restrict__ bits,
    const int* __restrict__ ntp, unsigned short* __restrict__ Ob)
{
    __shared__ unsigned short lds[16384];  // K0|K1|V0|V1, 4096 ushorts (64x64) each
    const int t = threadIdx.x, w = t >> 6, lane = t & 63;
    const int lo = lane & 15, hi = lane >> 4;
    const int qt = blockIdx.x, h = blockIdx.y, b = blockIdx.z;
    const int qr0 = qt * 128 + w * 32;
    const int l7 = lo & 7;
    const int nt = ntp[b];

    const int srow = lane >> 3;                 // 0..7 within 8-row sub-pass
    const int scb  = ((lane & 7) ^ srow) << 3;  // pre-swizzled source 16B block

    bf16x8 qf[2][2];
#pragma unroll
    for (int qh = 0; qh < 2; ++qh)
#pragma unroll
        for (int kk = 0; kk < 2; ++kk)
            qf[qh][kk] = *(const bf16x8*)&Q[(size_t)(b * S_ + qr0 + qh * 16 + lo) * DIM_ + h * 64 + kk * 32 + hi * 8];

    f32x4 zero4 = {0.f, 0.f, 0.f, 0.f};
    float mrow[2] = {-1e30f, -1e30f}, lsum[2] = {0.f, 0.f};
    f32x4 o[4][2];
#pragma unroll
    for (int dt = 0; dt < 4; ++dt)
#pragma unroll
        for (int qh = 0; qh < 2; ++qh) o[dt][qh] = zero4;

    // prologue: stage tile 0 into buf 0 (nt >= 1 always; tile 0 never empty)
#pragma unroll
    for (int s = 0; s < 2; ++s) {
        int rl = w * 16 + s * 8 + srow;
        GLOAD16(&Kb[(size_t)(b * SC_ + rl) * DIM_ + h * 64 + scb], &lds[(w * 16 + s * 8) * 64]);
        GLOAD16(&VT[(size_t)(b * 1024 + h * 64 + rl) * SC_ + scb], &lds[8192 + (w * 16 + s * 8) * 64]);
    }
    __syncthreads();

    int cur = 0;
    for (int tt = 0; tt < nt; ++tt) {
        if (tt + 1 < nt) {  // stage next tile (drains at this iter's barrier)
            int c0n = (tt + 1) * 64;
#pragma unroll
            for (int s = 0; s < 2; ++s) {
                int rl = w * 16 + s * 8 + srow;
                GLOAD16(&Kb[(size_t)(b * SC_ + c0n + rl) * DIM_ + h * 64 + scb],
                        &lds[(cur ^ 1) * 4096 + (w * 16 + s * 8) * 64]);
                GLOAD16(&VT[(size_t)(b * 1024 + h * 64 + rl) * SC_ + c0n + scb],
                        &lds[8192 + (cur ^ 1) * 4096 + (w * 16 + s * 8) * 64]);
            }
        }
        const unsigned short* Kl = &lds[cur * 4096];
        const unsigned short* Vl = &lds[8192 + cur * 4096];

        // QK^T (swapped): st[n][qh] rows kv = n*16+hi*4+r, cols q = lo (half qh)
        f32x4 st[4][2];
#pragma unroll
        for (int n = 0; n < 4; ++n)
#pragma unroll
            for (int qh = 0; qh < 2; ++qh) st[n][qh] = zero4;
#pragma unroll
        for (int n = 0; n < 4; ++n) {
            const int R = n * 16 + lo;
            bf16x8 k0 = *(const bf16x8*)&Kl[R * 64 + ((hi ^ l7) << 3)];
            bf16x8 k1 = *(const bf16x8*)&Kl[R * 64 + (((4 + hi) ^ l7) << 3)];
#pragma unroll
            for (int qh = 0; qh < 2; ++qh) {
                st[n][qh] = __builtin_amdgcn_mfma_f32_16x16x32_bf16(k0, qf[qh][0], st[n][qh], 0, 0, 0);
                st[n][qh] = __builtin_amdgcn_mfma_f32_16x16x32_bf16(k1, qf[qh][1], st[n][qh], 0, 0, 0);
            }
        }
        // V^T fragments for K=16 PV
        bf16x4 vf[4][4];
#pragma unroll
        for (int dt = 0; dt < 4; ++dt)
#pragma unroll
            for (int n = 0; n < 4; ++n)
                vf[dt][n] = *(const bf16x4*)&Vl[(dt * 16 + lo) * 64
                              + (((2 * n + (hi >> 1)) ^ l7) << 3) + ((hi & 1) << 2)];

        uint2 mw = *(const uint2*)&bits[b * 32 + tt * 2];

        // mask (scores already log2-scaled) + lane-local max
        float p[2][4][4];
        float mx[2] = {-1e30f, -1e30f};
        if ((mw.x | mw.y) == 0u) {  // wave-uniform: fully valid tile, skip mask math
#pragma unroll
            for (int n = 0; n < 4; ++n)
#pragma unroll
                for (int r = 0; r < 4; ++r)
#pragma unroll
                    for (int qh = 0; qh < 2; ++qh) {
                        float s = st[n][qh][r];
                        p[qh][n][r] = s;
                        mx[qh] = fmaxf(mx[qh], s);
                    }
        } else {  // R6-identical bitmask path
#pragma unroll
            for (int n = 0; n < 4; ++n) {
                unsigned int wd = (n & 2) ? mw.y : mw.x;
#pragma unroll
                for (int r = 0; r < 4; ++r) {
                    int sh = ((n & 1) << 4) + (hi << 2) + r;
                    bool mk = (wd >> sh) & 1u;
#pragma unroll
                    for (int qh = 0; qh < 2; ++qh) {
                        float s = mk ? -1e30f : st[n][qh][r];
                        p[qh][n][r] = s;
                        mx[qh] = fmaxf(mx[qh], s);
                    }
                }
            }
        }
        // per-tile rescale, base-2 domain (bare v_exp_f32 via builtin)
#pragma unroll
        for (int qh = 0; qh < 2; ++qh) {
            float m2 = fmaxf(mx[qh], __shfl_xor(mx[qh], 16));
            m2 = fmaxf(m2, __shfl_xor(m2, 32));
            float mnew = fmaxf(mrow[qh], m2);
            float scl = __builtin_amdgcn_exp2f(mrow[qh] - mnew);
            mrow[qh] = mnew;
            float rs = 0.f;
#pragma unroll
            for (int n = 0; n < 4; ++n)
#pragma unroll
                for (int r = 0; r < 4; ++r) {
                    float e = __builtin_amdgcn_exp2f(p[qh][n][r] - mnew);
                    p[qh][n][r] = e;
                    rs += e;
                }
            rs += __shfl_xor(rs, 16);
            rs += __shfl_xor(rs, 32);
            lsum[qh] = lsum[qh] * scl + rs;
#pragma unroll
            for (int dt = 0; dt < 4; ++dt)
#pragma unroll
                for (int r = 0; r < 4; ++r)
                    o[dt][qh][r] *= scl;
        }
        // pack P^T (manual RTNE, proven) and PV (K=16)
#pragma unroll
        for (int qh = 0; qh < 2; ++qh) {
#pragma unroll
            for (int n = 0; n < 4; ++n) {
                uint2 pk2;
                pk2.x = (unsigned int)f2bf(p[qh][n][0]) | ((unsigned int)f2bf(p[qh][n][1]) << 16);
                pk2.y = (unsigned int)f2bf(p[qh][n][2]) | ((unsigned int)f2bf(p[qh][n][3]) << 16);
                bf16x4 pb = __builtin_bit_cast(bf16x4, pk2);
#pragma unroll
                for (int dt = 0; dt < 4; ++dt)
                    o[dt][qh] = __builtin_amdgcn_mfma_f32_16x16x16bf16_1k(vf[dt][n], pb, o[dt][qh], 0, 0, 0);
            }
        }
        __syncthreads();  // drains stage vmcnt + all waves' LDS reads of buf[cur]
        cur ^= 1;
    }

    // epilogue: O^T -> O via wave-private LDS transpose
    unsigned short* Tl = &lds[w * 2304];  // [32][72]
    float inv[2] = {1.0f / lsum[0], 1.0f / lsum[1]};
#pragma unroll
    for (int qh = 0; qh < 2; ++qh)
#pragma unroll
        for (int dt = 0; dt < 4; ++dt)
#pragma unroll
            for (int r = 0; r < 4; ++r)
                Tl[(qh * 16 + lo) * 72 + dt * 16 + hi * 4 + r] = f2bf(o[dt][qh][r] * inv[qh]);
#pragma unroll
    for (int ps = 0; ps < 4; ++ps) {
        int row = ps * 8 + (lane >> 3);
        int col = (lane & 7) * 8;
        bf16x8 v = *(const bf16x8*)&Tl[row * 72 + col];
        *(bf16x8*)&Ob[(size_t)(b * S_ + qr0 + row) * DIM_ + h * 64 + col] = v;
    }
}

// ---------------- launch ----------------
extern "C" void kernel_launch(void* const* d_in, const int* in_sizes, int n_in,
                              void* d_out, int out_size, void* d_ws, size_t ws_size,
                              hipStream_t stream)
{
    const float* x  = (const float*)d_in[0];
    const float* cx = (const float*)d_in[1];
    const void* mask = d_in[2];
    const float* Wq = (const float*)d_in[3];
    const float* bq = (const float*)d_in[4];
    const float* Wk = (const float*)d_in[5];
    const float* bk = (const float*)d_in[6];
    const float* Wv = (const float*)d_in[7];
    const float* bv = (const float*)d_in[8];
    const float* Wo = (const float*)d_in[9];
    const float* bo = (const float*)d_in[10];

    unsigned short* ws = (unsigned short*)d_ws;
    const size_t XB  = 0;                                  // 8192*1024 (x bf16; later attn out)
    const size_t CXB = XB  + (size_t)8192 * 1024;          // 4096*768
    const size_t WQT = CXB + (size_t)4096 * 768;           // 1024*1024
    const size_t WKT = WQT + (size_t)1024 * 1024;          // 1024*768  \ contiguous = B^T(2048x768)
    const size_t WVT = WKT + (size_t)1024 * 768;           // 1024*768  /
    const size_t WOT = WVT + (size_t)1024 * 768;           // 1024*1024
    const size_t QB  = WOT + (size_t)1024 * 1024;          // 8192*1024
    const size_t KB  = QB  + (size_t)8192 * 1024;          // 4096*1024
    const size_t VTB = KB  + (size_t)4096 * 1024;          // 4*1024*1024
    const size_t MBT = VTB + (size_t)4 * 1024 * 1024;      // 128 uint32 = 256 ushort
    const size_t NTP = MBT + 256;                          // 4 ints

    k_f32_to_bf16<<<2048, 256, 0, stream>>>(x,  ws + XB,  8192 * 1024 / 4);
    k_f32_to_bf16<<<2048, 256, 0, stream>>>(cx, ws + CXB, 4096 * 768 / 4);
    k_transposeW<<<512, 256, 0, stream>>>(Wq, ws + WQT, 1024);
    k_transposeW<<<384, 256, 0, stream>>>(Wk, ws + WKT, 768);
    k_transposeW<<<384, 256, 0, stream>>>(Wv, ws + WVT, 768);
    k_transposeW<<<512, 256, 0, stream>>>(Wo, ws + WOT, 1024);
    unsigned int* mbits = (unsigned int*)(ws + MBT);
    int* ntp = (int*)(ws + NTP);
    k_mask_bits<<<1, 256, 0, stream>>>((const unsigned int*)mask, mbits, ntp);

    const float QSCALE = 0.125f * 1.44269504088896340736f;  // 1/sqrt(64) * log2(e) folded into Q
    dim3 gq(8192 / 128, 1024 / 128);
    dim3 gkv(4096 / 128, 2048 / 128);
    k_gemm_bt<0><<<gq, 256, 0, stream>>>(ws + XB, ws + WQT, bq, nullptr, QSCALE, ws + QB, nullptr, nullptr, 8192, 1024, 1024);
    // merged K|V projection: K rows -> KB, V^T -> VTB
    k_gemm_bt<3><<<gkv, 256, 0, stream>>>(ws + CXB, ws + WKT, bk, bv, 1.0f, ws + KB, ws + VTB, nullptr, 4096, 2048, 768);

    dim3 ga(S_ / 128, NH_, B_);
    k_attn<<<ga, 256, 0, stream>>>(ws + QB, ws + KB, ws + VTB, mbits, ntp, ws + XB);

    k_gemm_bt<2><<<gq, 256, 0, stream>>>(ws + XB, ws + WOT, bo, nullptr, 1.0f, nullptr, nullptr, (float*)d_out, 8192, 1024, 1024);
}

// Round 9
// 187.602 us; speedup vs baseline: 1.2275x; 1.0489x over previous
//
#include <hip/hip_runtime.h>
#include <hip/hip_bf16.h>
#include <stdint.h>

#define DIM_ 1024
#define NH_ 16
#define HD_ 64
#define B_ 4
#define S_ 2048
#define SC_ 1024
#define CD_ 768

typedef __attribute__((ext_vector_type(8))) short bf16x8;
typedef __attribute__((ext_vector_type(4))) short bf16x4;
typedef __attribute__((ext_vector_type(4))) float f32x4;

// native bf16 cast (RTNE) -- compiler lowers pairs to v_cvt_pk_bf16_f32 (m240)
__device__ inline unsigned short f2bf(float f) {
    __hip_bfloat16 h = __float2bfloat16(f);
    return __builtin_bit_cast(unsigned short, h);
}

#define GLOAD16(SRC, DST) __builtin_amdgcn_global_load_lds( \
    (const __attribute__((address_space(1))) void*)(SRC),   \
    (__attribute__((address_space(3))) void*)(DST), 16, 0, 0)

// ---------------- conversion kernels ----------------
__global__ void k_f32_to_bf16(const float* __restrict__ in, unsigned short* __restrict__ out, int n4) {
    int i = blockIdx.x * blockDim.x + threadIdx.x;
    int stride = gridDim.x * blockDim.x;
    for (; i < n4; i += stride) {
        float4 v = ((const float4*)in)[i];
        uint2 pk;
        pk.x = (unsigned int)f2bf(v.x) | ((unsigned int)f2bf(v.y) << 16);
        pk.y = (unsigned int)f2bf(v.z) | ((unsigned int)f2bf(v.w) << 16);
        ((uint2*)out)[i] = pk;
    }
}

// W is (K x 1024) -> WT (1024 x K) bf16; coalesced reads, 16B writes
__global__ void k_transposeW(const float* __restrict__ W, unsigned short* __restrict__ WT, int K) {
    int idx = blockIdx.x * blockDim.x + threadIdx.x;
    if (idx >= (K >> 3) * 1024) return;
    int n = idx & 1023;
    int k0 = (idx >> 10) << 3;
    unsigned int pk[4];
#pragma unroll
    for (int j = 0; j < 4; ++j) {
        unsigned short a = f2bf(W[(size_t)(k0 + 2 * j) * 1024 + n]);
        unsigned short b = f2bf(W[(size_t)(k0 + 2 * j + 1) * 1024 + n]);
        pk[j] = (unsigned int)a | ((unsigned int)b << 16);
    }
    *(uint4*)&WT[(size_t)n * K + k0] = *(uint4*)pk;
}

// per-batch key-padding bitmask (bit=1 -> masked) + nt[b] = (last tile with any
// valid key)+1. Handles byte-bool or int32 mask upload.
__global__ void k_mask_bits(const unsigned int* __restrict__ m,
                            unsigned int* __restrict__ bits, int* __restrict__ ntp) {
    __shared__ int bm_s;
    __shared__ unsigned int wbits[128];
    if (threadIdx.x == 0) bm_s = 0;
    __syncthreads();
    int any = 0;
    for (int i = threadIdx.x; i < 1024; i += 256)  // first 4096 bytes: safe both modes
        if (m[i] > 1u) any = 1;
    if (any) atomicOr(&bm_s, 1);
    __syncthreads();
    const int boolmode = bm_s;
    const int w = threadIdx.x;
    if (w < 128) {
        const unsigned char* mb = (const unsigned char*)m;
        unsigned int out = 0;
        for (int j = 0; j < 32; ++j) {
            int c = w * 32 + j;
            int masked = boolmode ? (mb[c] != 0) : (m[c] != 0u);
            out |= (unsigned int)masked << j;
        }
        bits[w] = out;
        wbits[w] = out;
    }
    __syncthreads();
    if (threadIdx.x < 4) {
        int nt = 0;
        for (int tt = 0; tt < 16; ++tt) {
            unsigned int w0 = wbits[threadIdx.x * 32 + tt * 2];
            unsigned int w1 = wbits[threadIdx.x * 32 + tt * 2 + 1];
            if ((w0 & w1) != 0xFFFFFFFFu) nt = tt + 1;  // tile has >=1 valid key
        }
        ntp[threadIdx.x] = nt;
    }
}

// ---------------- bf16 GEMM, B^T layout, double-buffered global_load_lds staging ----------------
// One barrier per K-step (attn-proven pattern): stage(t+1) issued before compute(t);
// the pre-barrier vmcnt(0) drain lands it; reads of buf[cur] complete before barrier.
// C = (A * BT^T + bias) * oscale.  T1 XCD-swizzle (all grids nwg%8==0).
// EPI 0: bf16 row-major. EPI 2: f32 row-major. EPI 3: merged K|V.
template<int EPI>
__global__ __launch_bounds__(256) void k_gemm_bt(
    const unsigned short* __restrict__ A, const unsigned short* __restrict__ BT,
    const float* __restrict__ bias, const float* __restrict__ bias2, float oscale,
    unsigned short* __restrict__ Cb, unsigned short* __restrict__ Cb2,
    float* __restrict__ Cf, int M, int N, int K)
{
    __shared__ unsigned short As[2][128 * 32];
    __shared__ unsigned short Bs[2][128 * 32];
    const int t = threadIdx.x;
    const int w = t >> 6, lane = t & 63;
    const int lo = lane & 15, hi = lane >> 4;
    const int nwg = gridDim.x * gridDim.y;
    const int wg = blockIdx.y * gridDim.x + blockIdx.x;
    const int swz = (wg & 7) * (nwg >> 3) + (wg >> 3);
    const int m0 = (swz % gridDim.x) * 128, n0 = (swz / gridDim.x) * 128;
    const int wr = (w >> 1) * 64, wc = (w & 1) * 64;
    const int srow = lane >> 2;
    const int scol = (lane & 3) * 8;

    f32x4 zero4 = {0.f, 0.f, 0.f, 0.f};
    f32x4 acc[4][4];
    for (int i = 0; i < 4; ++i)
        for (int j = 0; j < 4; ++j) acc[i][j] = zero4;

    // prologue: stage k0=0 into buf 0
#pragma unroll
    for (int p = 0; p < 2; ++p) {
        int chunk = w * 2 + p;
        int r = chunk * 16 + srow;
        GLOAD16(&A[(size_t)(m0 + r) * K + scol], &As[0][chunk * 512]);
        GLOAD16(&BT[(size_t)(n0 + r) * K + scol], &Bs[0][chunk * 512]);
    }
    __syncthreads();

    int cur = 0;
    for (int k0 = 0; k0 < K; k0 += 32) {
        if (k0 + 32 < K) {  // stage next K-slice into other buffer
#pragma unroll
            for (int p = 0; p < 2; ++p) {
                int chunk = w * 2 + p;
                int r = chunk * 16 + srow;
                GLOAD16(&A[(size_t)(m0 + r) * K + k0 + 32 + scol], &As[cur ^ 1][chunk * 512]);
                GLOAD16(&BT[(size_t)(n0 + r) * K + k0 + 32 + scol], &Bs[cur ^ 1][chunk * 512]);
            }
        }
        bf16x8 af[4], bfr[4];
#pragma unroll
        for (int i = 0; i < 4; ++i)
            af[i] = *(const bf16x8*)&As[cur][(wr + i * 16 + lo) * 32 + (hi << 3)];
#pragma unroll
        for (int j = 0; j < 4; ++j)
            bfr[j] = *(const bf16x8*)&Bs[cur][(wc + j * 16 + lo) * 32 + (hi << 3)];
#pragma unroll
        for (int i = 0; i < 4; ++i)
#pragma unroll
            for (int j = 0; j < 4; ++j)
                acc[i][j] = __builtin_amdgcn_mfma_f32_16x16x32_bf16(af[i], bfr[j], acc[i][j], 0, 0, 0);
        __syncthreads();  // reads of buf[cur] done; staged buf[cur^1] landed (vmcnt drain)
        cur ^= 1;
    }

#pragma unroll
    for (int i = 0; i < 4; ++i) {
#pragma unroll
        for (int j = 0; j < 4; ++j) {
#pragma unroll
            for (int r = 0; r < 4; ++r) {
                int m = m0 + wr + i * 16 + (hi << 2) + r;
                int n = n0 + wc + j * 16 + lo;
                if (EPI == 0) {
                    float v = (acc[i][j][r] + bias[n]) * oscale;
                    Cb[(size_t)m * 1024 + n] = f2bf(v);
                } else if (EPI == 2) {
                    float v = (acc[i][j][r] + bias[n]) * oscale;
                    Cf[(size_t)m * 1024 + n] = v;
                } else if (EPI == 3) {
                    if (n < 1024) {
                        float v = acc[i][j][r] + bias[n];
                        Cb[(size_t)m * 1024 + n] = f2bf(v);
                    } else {
                        float v = acc[i][j][r] + bias2[n - 1024];
                        int bb = m >> 10, c = m & 1023;
                        Cb2[(size_t)((bb << 10) + (n - 1024)) * 1024 + c] = f2bf(v);
                    }
                }
            }
        }
    }
}

// ---------------- fused flash attention ----------------
// LDS-staged K/V (double-buffered, XOR-swizzled both sides), swapped-QK^T,
// base-2 in-register softmax (Q pre-scaled by 0.125*log2e), tile-skip via nt[b],
// wave-uniform no-mask fast path, T13 defer-max (THR=8).
__global__ __launch_bounds__(256) void k_attn(
    const unsigned short* __restrict__ Q, const unsigned short* __restrict__ Kb,
    const unsigned short* __restrict__ VT, const unsigned int* __restrict__ bits,
    const int* __restrict__ ntp, unsigned short* __restrict__ Ob)
{
    __shared__ unsigned short lds[16384];  // K0|K1|V0|V1, 4096 ushorts (64x64) each
    const int t = threadIdx.x, w = t >> 6, lane = t & 63;
    const int lo = lane & 15, hi = lane >> 4;
    const int qt = blockIdx.x, h = blockIdx.y, b = blockIdx.z;
    const int qr0 = qt * 128 + w * 32;
    const int l7 = lo & 7;
    const int nt = ntp[b];

    const int srow = lane >> 3;                 // 0..7 within 8-row sub-pass
    const int scb  = ((lane & 7) ^ srow) << 3;  // pre-swizzled source 16B block

    bf16x8 qf[2][2];
#pragma unroll
    for (int qh = 0; qh < 2; ++qh)
#pragma unroll
        for (int kk = 0; kk < 2; ++kk)
            qf[qh][kk] = *(const bf16x8*)&Q[(size_t)(b * S_ + qr0 + qh * 16 + lo) * DIM_ + h * 64 + kk * 32 + hi * 8];

    f32x4 zero4 = {0.f, 0.f, 0.f, 0.f};
    float mrow[2] = {-1e30f, -1e30f}, lsum[2] = {0.f, 0.f};
    f32x4 o[4][2];
#pragma unroll
    for (int dt = 0; dt < 4; ++dt)
#pragma unroll
        for (int qh = 0; qh < 2; ++qh) o[dt][qh] = zero4;

    // prologue: stage tile 0 into buf 0
#pragma unroll
    for (int s = 0; s < 2; ++s) {
        int rl = w * 16 + s * 8 + srow;
        GLOAD16(&Kb[(size_t)(b * SC_ + rl) * DIM_ + h * 64 + scb], &lds[(w * 16 + s * 8) * 64]);
        GLOAD16(&VT[(size_t)(b * 1024 + h * 64 + rl) * SC_ + scb], &lds[8192 + (w * 16 + s * 8) * 64]);
    }
    __syncthreads();

    int cur = 0;
    for (int tt = 0; tt < nt; ++tt) {
        if (tt + 1 < nt) {  // stage next tile (drains at this iter's barrier)
            int c0n = (tt + 1) * 64;
#pragma unroll
            for (int s = 0; s < 2; ++s) {
                int rl = w * 16 + s * 8 + srow;
                GLOAD16(&Kb[(size_t)(b * SC_ + c0n + rl) * DIM_ + h * 64 + scb],
                        &lds[(cur ^ 1) * 4096 + (w * 16 + s * 8) * 64]);
                GLOAD16(&VT[(size_t)(b * 1024 + h * 64 + rl) * SC_ + c0n + scb],
                        &lds[8192 + (cur ^ 1) * 4096 + (w * 16 + s * 8) * 64]);
            }
        }
        const unsigned short* Kl = &lds[cur * 4096];
        const unsigned short* Vl = &lds[8192 + cur * 4096];

        // QK^T (swapped): st[n][qh] rows kv = n*16+hi*4+r, cols q = lo (half qh)
        f32x4 st[4][2];
#pragma unroll
        for (int n = 0; n < 4; ++n)
#pragma unroll
            for (int qh = 0; qh < 2; ++qh) st[n][qh] = zero4;
#pragma unroll
        for (int n = 0; n < 4; ++n) {
            const int R = n * 16 + lo;
            bf16x8 k0 = *(const bf16x8*)&Kl[R * 64 + ((hi ^ l7) << 3)];
            bf16x8 k1 = *(const bf16x8*)&Kl[R * 64 + (((4 + hi) ^ l7) << 3)];
#pragma unroll
            for (int qh = 0; qh < 2; ++qh) {
                st[n][qh] = __builtin_amdgcn_mfma_f32_16x16x32_bf16(k0, qf[qh][0], st[n][qh], 0, 0, 0);
                st[n][qh] = __builtin_amdgcn_mfma_f32_16x16x32_bf16(k1, qf[qh][1], st[n][qh], 0, 0, 0);
            }
        }
        // V^T fragments for K=16 PV
        bf16x4 vf[4][4];
#pragma unroll
        for (int dt = 0; dt < 4; ++dt)
#pragma unroll
            for (int n = 0; n < 4; ++n)
                vf[dt][n] = *(const bf16x4*)&Vl[(dt * 16 + lo) * 64
                              + (((2 * n + (hi >> 1)) ^ l7) << 3) + ((hi & 1) << 2)];

        uint2 mw = *(const uint2*)&bits[b * 32 + tt * 2];

        // mask (scores already log2-scaled) + lane-local max
        float p[2][4][4];
        float mx[2] = {-1e30f, -1e30f};
        if ((mw.x | mw.y) == 0u) {  // wave-uniform: fully valid tile, skip mask math
#pragma unroll
            for (int n = 0; n < 4; ++n)
#pragma unroll
                for (int r = 0; r < 4; ++r)
#pragma unroll
                    for (int qh = 0; qh < 2; ++qh) {
                        float s = st[n][qh][r];
                        p[qh][n][r] = s;
                        mx[qh] = fmaxf(mx[qh], s);
                    }
        } else {  // bitmask path (R6-proven)
#pragma unroll
            for (int n = 0; n < 4; ++n) {
                unsigned int wd = (n & 2) ? mw.y : mw.x;
#pragma unroll
                for (int r = 0; r < 4; ++r) {
                    int sh = ((n & 1) << 4) + (hi << 2) + r;
                    bool mk = (wd >> sh) & 1u;
#pragma unroll
                    for (int qh = 0; qh < 2; ++qh) {
                        float s = mk ? -1e30f : st[n][qh][r];
                        p[qh][n][r] = s;
                        mx[qh] = fmaxf(mx[qh], s);
                    }
                }
            }
        }
        float m2[2];
#pragma unroll
        for (int qh = 0; qh < 2; ++qh) {
            float v = fmaxf(mx[qh], __shfl_xor(mx[qh], 16));
            m2[qh] = fmaxf(v, __shfl_xor(v, 32));
        }
        // T13 defer-max: skip rescale while max growth <= 8 for every row in wave
        // (deferred tiles: p - mrow <= 8 -> e <= 256, safe in f32/bf16)
        float growth = fmaxf(m2[0] - mrow[0], m2[1] - mrow[1]);
        if (!__all(growth <= 8.0f)) {
#pragma unroll
            for (int qh = 0; qh < 2; ++qh) {
                float mnew = fmaxf(mrow[qh], m2[qh]);
                float scl = __builtin_amdgcn_exp2f(mrow[qh] - mnew);
                mrow[qh] = mnew;
                lsum[qh] *= scl;
#pragma unroll
                for (int dt = 0; dt < 4; ++dt)
#pragma unroll
                    for (int r = 0; r < 4; ++r)
                        o[dt][qh][r] *= scl;
            }
        }
#pragma unroll
        for (int qh = 0; qh < 2; ++qh) {
            float rs = 0.f;
#pragma unroll
            for (int n = 0; n < 4; ++n)
#pragma unroll
                for (int r = 0; r < 4; ++r) {
                    float e = __builtin_amdgcn_exp2f(p[qh][n][r] - mrow[qh]);
                    p[qh][n][r] = e;
                    rs += e;
                }
            rs += __shfl_xor(rs, 16);
            rs += __shfl_xor(rs, 32);
            lsum[qh] += rs;
        }
        // pack P^T (native bf16 casts -> compiler cvt_pk) and PV (K=16)
#pragma unroll
        for (int qh = 0; qh < 2; ++qh) {
#pragma unroll
            for (int n = 0; n < 4; ++n) {
                uint2 pk2;
                pk2.x = (unsigned int)f2bf(p[qh][n][0]) | ((unsigned int)f2bf(p[qh][n][1]) << 16);
                pk2.y = (unsigned int)f2bf(p[qh][n][2]) | ((unsigned int)f2bf(p[qh][n][3]) << 16);
                bf16x4 pb = __builtin_bit_cast(bf16x4, pk2);
#pragma unroll
                for (int dt = 0; dt < 4; ++dt)
                    o[dt][qh] = __builtin_amdgcn_mfma_f32_16x16x16bf16_1k(vf[dt][n], pb, o[dt][qh], 0, 0, 0);
            }
        }
        __syncthreads();  // drains stage vmcnt + all waves' LDS reads of buf[cur]
        cur ^= 1;
    }

    // epilogue: O^T -> O via wave-private LDS transpose
    unsigned short* Tl = &lds[w * 2304];  // [32][72]
    float inv[2] = {1.0f / lsum[0], 1.0f / lsum[1]};
#pragma unroll
    for (int qh = 0; qh < 2; ++qh)
#pragma unroll
        for (int dt = 0; dt < 4; ++dt)
#pragma unroll
            for (int r = 0; r < 4; ++r)
                Tl[(qh * 16 + lo) * 72 + dt * 16 + hi * 4 + r] = f2bf(o[dt][qh][r] * inv[qh]);
#pragma unroll
    for (int ps = 0; ps < 4; ++ps) {
        int row = ps * 8 + (lane >> 3);
        int col = (lane & 7) * 8;
        bf16x8 v = *(const bf16x8*)&Tl[row * 72 + col];
        *(bf16x8*)&Ob[(size_t)(b * S_ + qr0 + row) * DIM_ + h * 64 + col] = v;
    }
}

// ---------------- launch ----------------
extern "C" void kernel_launch(void* const* d_in, const int* in_sizes, int n_in,
                              void* d_out, int out_size, void* d_ws, size_t ws_size,
                              hipStream_t stream)
{
    const float* x  = (const float*)d_in[0];
    const float* cx = (const float*)d_in[1];
    const void* mask = d_in[2];
    const float* Wq = (const float*)d_in[3];
    const float* bq = (const float*)d_in[4];
    const float* Wk = (const float*)d_in[5];
    const float* bk = (const float*)d_in[6];
    const float* Wv = (const float*)d_in[7];
    const float* bv = (const float*)d_in[8];
    const float* Wo = (const float*)d_in[9];
    const float* bo = (const float*)d_in[10];

    unsigned short* ws = (unsigned short*)d_ws;
    const size_t XB  = 0;                                  // 8192*1024 (x bf16; later attn out)
    const size_t CXB = XB  + (size_t)8192 * 1024;          // 4096*768
    const size_t WQT = CXB + (size_t)4096 * 768;           // 1024*1024
    const size_t WKT = WQT + (size_t)1024 * 1024;          // 1024*768  \ contiguous = B^T(2048x768)
    const size_t WVT = WKT + (size_t)1024 * 768;           // 1024*768  /
    const size_t WOT = WVT + (size_t)1024 * 768;           // 1024*1024
    const size_t QB  = WOT + (size_t)1024 * 1024;          // 8192*1024
    const size_t KB  = QB  + (size_t)8192 * 1024;          // 4096*1024
    const size_t VTB = KB  + (size_t)4096 * 1024;          // 4*1024*1024
    const size_t MBT = VTB + (size_t)4 * 1024 * 1024;      // 128 uint32 = 256 ushort
    const size_t NTP = MBT + 256;                          // 4 ints

    k_f32_to_bf16<<<2048, 256, 0, stream>>>(x,  ws + XB,  8192 * 1024 / 4);
    k_f32_to_bf16<<<2048, 256, 0, stream>>>(cx, ws + CXB, 4096 * 768 / 4);
    k_transposeW<<<512, 256, 0, stream>>>(Wq, ws + WQT, 1024);
    k_transposeW<<<384, 256, 0, stream>>>(Wk, ws + WKT, 768);
    k_transposeW<<<384, 256, 0, stream>>>(Wv, ws + WVT, 768);
    k_transposeW<<<512, 256, 0, stream>>>(Wo, ws + WOT, 1024);
    unsigned int* mbits = (unsigned int*)(ws + MBT);
    int* ntp = (int*)(ws + NTP);
    k_mask_bits<<<1, 256, 0, stream>>>((const unsigned int*)mask, mbits, ntp);

    const float QSCALE = 0.125f * 1.44269504088896340736f;  // 1/sqrt(64) * log2(e) folded into Q
    dim3 gq(8192 / 128, 1024 / 128);
    dim3 gkv(4096 / 128, 2048 / 128);
    k_gemm_bt<0><<<gq, 256, 0, stream>>>(ws + XB, ws + WQT, bq, nullptr, QSCALE, ws + QB, nullptr, nullptr, 8192, 1024, 1024);
    // merged K|V projection: K rows -> KB, V^T -> VTB
    k_gemm_bt<3><<<gkv, 256, 0, stream>>>(ws + CXB, ws + WKT, bk, bv, 1.0f, ws + KB, ws + VTB, nullptr, 4096, 2048, 768);

    dim3 ga(S_ / 128, NH_, B_);
    k_attn<<<ga, 256, 0, stream>>>(ws + QB, ws + KB, ws + VTB, mbits, ntp, ws + XB);

    k_gemm_bt<2><<<gq, 256, 0, stream>>>(ws + XB, ws + WOT, bo, nullptr, 1.0f, nullptr, nullptr, (float*)d_out, 8192, 1024, 1024);
}

// Round 10
// 170.711 us; speedup vs baseline: 1.3489x; 1.0989x over previous
//
#include <hip/hip_runtime.h>
#include <hip/hip_bf16.h>
#include <stdint.h>

#define DIM_ 1024
#define NH_ 16
#define HD_ 64
#define B_ 4
#define S_ 2048
#define SC_ 1024
#define CD_ 768

typedef __attribute__((ext_vector_type(8))) short bf16x8;
typedef __attribute__((ext_vector_type(4))) short bf16x4;
typedef __attribute__((ext_vector_type(4))) float f32x4;

// native bf16 cast (RTNE) -- compiler lowers pairs to v_cvt_pk_bf16_f32
__device__ inline unsigned short f2bf(float f) {
    __hip_bfloat16 h = __float2bfloat16(f);
    return __builtin_bit_cast(unsigned short, h);
}

__device__ inline f32x4 vmax4(f32x4 a, f32x4 b) {
    f32x4 r;
#pragma unroll
    for (int i = 0; i < 4; ++i) r[i] = fmaxf(a[i], b[i]);
    return r;
}

#define GLOAD16(SRC, DST) __builtin_amdgcn_global_load_lds( \
    (const __attribute__((address_space(1))) void*)(SRC),   \
    (__attribute__((address_space(3))) void*)(DST), 16, 0, 0)

// ---------------- conversion kernels ----------------
__global__ void k_f32_to_bf16(const float* __restrict__ in, unsigned short* __restrict__ out, int n4) {
    int i = blockIdx.x * blockDim.x + threadIdx.x;
    int stride = gridDim.x * blockDim.x;
    for (; i < n4; i += stride) {
        float4 v = ((const float4*)in)[i];
        uint2 pk;
        pk.x = (unsigned int)f2bf(v.x) | ((unsigned int)f2bf(v.y) << 16);
        pk.y = (unsigned int)f2bf(v.z) | ((unsigned int)f2bf(v.w) << 16);
        ((uint2*)out)[i] = pk;
    }
}

// All 4 weight transposes in one launch. W (K x 1024) -> WT (1024 x K) bf16.
// Work item = one 16B output chunk (8 consecutive k for one n).
__global__ void k_transposeW4(const float* __restrict__ Wq, const float* __restrict__ Wk,
                              const float* __restrict__ Wv, const float* __restrict__ Wo,
                              unsigned short* __restrict__ WQT, unsigned short* __restrict__ WKT,
                              unsigned short* __restrict__ WVT, unsigned short* __restrict__ WOT) {
    int idx = blockIdx.x * blockDim.x + threadIdx.x;
    const float* W; unsigned short* WT; int K;
    if (idx < 131072)      { W = Wq; WT = WQT; K = 1024; }
    else if (idx < 229376) { W = Wk; WT = WKT; K = 768;  idx -= 131072; }
    else if (idx < 327680) { W = Wv; WT = WVT; K = 768;  idx -= 229376; }
    else                   { W = Wo; WT = WOT; K = 1024; idx -= 327680; }
    int n = idx & 1023;
    int k0 = (idx >> 10) << 3;
    unsigned int pk[4];
#pragma unroll
    for (int j = 0; j < 4; ++j) {
        unsigned short a = f2bf(W[(size_t)(k0 + 2 * j) * 1024 + n]);
        unsigned short b = f2bf(W[(size_t)(k0 + 2 * j + 1) * 1024 + n]);
        pk[j] = (unsigned int)a | ((unsigned int)b << 16);
    }
    *(uint4*)&WT[(size_t)n * K + k0] = *(uint4*)pk;
}

// per-batch key-padding bitmask (bit=1 -> masked) + nt[b] = (last tile with any
// valid key)+1. Handles byte-bool or int32 mask upload.
__global__ void k_mask_bits(const unsigned int* __restrict__ m,
                            unsigned int* __restrict__ bits, int* __restrict__ ntp) {
    __shared__ int bm_s;
    __shared__ unsigned int wbits[128];
    if (threadIdx.x == 0) bm_s = 0;
    __syncthreads();
    int any = 0;
    for (int i = threadIdx.x; i < 1024; i += 256)  // first 4096 bytes: safe both modes
        if (m[i] > 1u) any = 1;
    if (any) atomicOr(&bm_s, 1);
    __syncthreads();
    const int boolmode = bm_s;
    const int w = threadIdx.x;
    if (w < 128) {
        const unsigned char* mb = (const unsigned char*)m;
        unsigned int out = 0;
        for (int j = 0; j < 32; ++j) {
            int c = w * 32 + j;
            int masked = boolmode ? (mb[c] != 0) : (m[c] != 0u);
            out |= (unsigned int)masked << j;
        }
        bits[w] = out;
        wbits[w] = out;
    }
    __syncthreads();
    if (threadIdx.x < 4) {
        int nt = 0;
        for (int tt = 0; tt < 16; ++tt) {
            unsigned int w0 = wbits[threadIdx.x * 32 + tt * 2];
            unsigned int w1 = wbits[threadIdx.x * 32 + tt * 2 + 1];
            if ((w0 & w1) != 0xFFFFFFFFu) nt = tt + 1;  // tile has >=1 valid key
        }
        ntp[threadIdx.x] = nt;
    }
}

// ---------------- bf16 GEMM, B^T layout, double-buffered global_load_lds staging ----------------
// One barrier per K-step. C = (A * BT^T + bias) * oscale. T1 XCD-swizzle.
// EPI 0: bf16 row-major. EPI 2: f32 row-major. EPI 3: merged K|V (V^T half uses
// packed 8B stores: lane holds 4 consecutive c for one d).
template<int EPI>
__global__ __launch_bounds__(256) void k_gemm_bt(
    const unsigned short* __restrict__ A, const unsigned short* __restrict__ BT,
    const float* __restrict__ bias, const float* __restrict__ bias2, float oscale,
    unsigned short* __restrict__ Cb, unsigned short* __restrict__ Cb2,
    float* __restrict__ Cf, int M, int N, int K)
{
    __shared__ unsigned short As[2][128 * 32];
    __shared__ unsigned short Bs[2][128 * 32];
    const int t = threadIdx.x;
    const int w = t >> 6, lane = t & 63;
    const int lo = lane & 15, hi = lane >> 4;
    const int nwg = gridDim.x * gridDim.y;
    const int wg = blockIdx.y * gridDim.x + blockIdx.x;
    const int swz = (wg & 7) * (nwg >> 3) + (wg >> 3);
    const int m0 = (swz % gridDim.x) * 128, n0 = (swz / gridDim.x) * 128;
    const int wr = (w >> 1) * 64, wc = (w & 1) * 64;
    const int srow = lane >> 2;
    const int scol = (lane & 3) * 8;

    f32x4 zero4 = {0.f, 0.f, 0.f, 0.f};
    f32x4 acc[4][4];
    for (int i = 0; i < 4; ++i)
        for (int j = 0; j < 4; ++j) acc[i][j] = zero4;

    // prologue: stage k0=0 into buf 0
#pragma unroll
    for (int p = 0; p < 2; ++p) {
        int chunk = w * 2 + p;
        int r = chunk * 16 + srow;
        GLOAD16(&A[(size_t)(m0 + r) * K + scol], &As[0][chunk * 512]);
        GLOAD16(&BT[(size_t)(n0 + r) * K + scol], &Bs[0][chunk * 512]);
    }
    __syncthreads();

    int cur = 0;
    for (int k0 = 0; k0 < K; k0 += 32) {
        if (k0 + 32 < K) {  // stage next K-slice into other buffer
#pragma unroll
            for (int p = 0; p < 2; ++p) {
                int chunk = w * 2 + p;
                int r = chunk * 16 + srow;
                GLOAD16(&A[(size_t)(m0 + r) * K + k0 + 32 + scol], &As[cur ^ 1][chunk * 512]);
                GLOAD16(&BT[(size_t)(n0 + r) * K + k0 + 32 + scol], &Bs[cur ^ 1][chunk * 512]);
            }
        }
        bf16x8 af[4], bfr[4];
#pragma unroll
        for (int i = 0; i < 4; ++i)
            af[i] = *(const bf16x8*)&As[cur][(wr + i * 16 + lo) * 32 + (hi << 3)];
#pragma unroll
        for (int j = 0; j < 4; ++j)
            bfr[j] = *(const bf16x8*)&Bs[cur][(wc + j * 16 + lo) * 32 + (hi << 3)];
#pragma unroll
        for (int i = 0; i < 4; ++i)
#pragma unroll
            for (int j = 0; j < 4; ++j)
                acc[i][j] = __builtin_amdgcn_mfma_f32_16x16x32_bf16(af[i], bfr[j], acc[i][j], 0, 0, 0);
        __syncthreads();  // reads of buf[cur] done; staged buf[cur^1] landed (vmcnt drain)
        cur ^= 1;
    }

#pragma unroll
    for (int i = 0; i < 4; ++i) {
#pragma unroll
        for (int j = 0; j < 4; ++j) {
            int n = n0 + wc + j * 16 + lo;
            int mbase = m0 + wr + i * 16 + (hi << 2);
            if (EPI == 3 && n >= 1024) {
                // V^T half: lane holds 4 consecutive c (= mbase+r) for column d.
                // Pack to one 8B store (mbase%4==0 -> aligned, no 1024-crossing).
                float b2 = bias2[n - 1024];
                uint2 pk;
                pk.x = (unsigned int)f2bf(acc[i][j][0] + b2) | ((unsigned int)f2bf(acc[i][j][1] + b2) << 16);
                pk.y = (unsigned int)f2bf(acc[i][j][2] + b2) | ((unsigned int)f2bf(acc[i][j][3] + b2) << 16);
                int bb = mbase >> 10, c = mbase & 1023;
                *(uint2*)&Cb2[(size_t)((bb << 10) + (n - 1024)) * 1024 + c] = pk;
            } else {
#pragma unroll
                for (int r = 0; r < 4; ++r) {
                    int m = mbase + r;
                    if (EPI == 0) {
                        float v = (acc[i][j][r] + bias[n]) * oscale;
                        Cb[(size_t)m * 1024 + n] = f2bf(v);
                    } else if (EPI == 2) {
                        float v = (acc[i][j][r] + bias[n]) * oscale;
                        Cf[(size_t)m * 1024 + n] = v;
                    } else {  // EPI 3, K half
                        float v = acc[i][j][r] + bias[n];
                        Cb[(size_t)m * 1024 + n] = f2bf(v);
                    }
                }
            }
        }
    }
}

// ---------------- fused flash attention ----------------
// LDS-staged K/V (double-buffered, XOR-swizzled both sides), swapped-QK^T,
// base-2 in-register softmax (Q pre-scaled by 0.125*log2e), tile-skip via nt[b],
// wave-uniform no-mask fast path (vectorized), T13 defer-max (THR=8).
__global__ __launch_bounds__(256) void k_attn(
    const unsigned short* __restrict__ Q, const unsigned short* __restrict__ Kb,
    const unsigned short* __restrict__ VT, const unsigned int* __restrict__ bits,
    const int* __restrict__ ntp, unsigned short* __restrict__ Ob)
{
    __shared__ unsigned short lds[16384];  // K0|K1|V0|V1, 4096 ushorts (64x64) each
    const int t = threadIdx.x, w = t >> 6, lane = t & 63;
    const int lo = lane & 15, hi = lane >> 4;
    const int qt = blockIdx.x, h = blockIdx.y, b = blockIdx.z;
    const int qr0 = qt * 128 + w * 32;
    const int l7 = lo & 7;
    const int nt = ntp[b];

    const int srow = lane >> 3;                 // 0..7 within 8-row sub-pass
    const int scb  = ((lane & 7) ^ srow) << 3;  // pre-swizzled source 16B block

    bf16x8 qf[2][2];
#pragma unroll
    for (int qh = 0; qh < 2; ++qh)
#pragma unroll
        for (int kk = 0; kk < 2; ++kk)
            qf[qh][kk] = *(const bf16x8*)&Q[(size_t)(b * S_ + qr0 + qh * 16 + lo) * DIM_ + h * 64 + kk * 32 + hi * 8];

    f32x4 zero4 = {0.f, 0.f, 0.f, 0.f};
    float mrow[2] = {-1e30f, -1e30f}, lsum[2] = {0.f, 0.f};
    f32x4 o[4][2];
#pragma unroll
    for (int dt = 0; dt < 4; ++dt)
#pragma unroll
        for (int qh = 0; qh < 2; ++qh) o[dt][qh] = zero4;

    // prologue: stage tile 0 into buf 0
#pragma unroll
    for (int s = 0; s < 2; ++s) {
        int rl = w * 16 + s * 8 + srow;
        GLOAD16(&Kb[(size_t)(b * SC_ + rl) * DIM_ + h * 64 + scb], &lds[(w * 16 + s * 8) * 64]);
        GLOAD16(&VT[(size_t)(b * 1024 + h * 64 + rl) * SC_ + scb], &lds[8192 + (w * 16 + s * 8) * 64]);
    }
    __syncthreads();

    int cur = 0;
    for (int tt = 0; tt < nt; ++tt) {
        if (tt + 1 < nt) {  // stage next tile (drains at this iter's barrier)
            int c0n = (tt + 1) * 64;
#pragma unroll
            for (int s = 0; s < 2; ++s) {
                int rl = w * 16 + s * 8 + srow;
                GLOAD16(&Kb[(size_t)(b * SC_ + c0n + rl) * DIM_ + h * 64 + scb],
                        &lds[(cur ^ 1) * 4096 + (w * 16 + s * 8) * 64]);
                GLOAD16(&VT[(size_t)(b * 1024 + h * 64 + rl) * SC_ + c0n + scb],
                        &lds[8192 + (cur ^ 1) * 4096 + (w * 16 + s * 8) * 64]);
            }
        }
        const unsigned short* Kl = &lds[cur * 4096];
        const unsigned short* Vl = &lds[8192 + cur * 4096];

        // QK^T (swapped): st[n][qh] rows kv = n*16+hi*4+r, cols q = lo (half qh)
        f32x4 st[4][2];
#pragma unroll
        for (int n = 0; n < 4; ++n)
#pragma unroll
            for (int qh = 0; qh < 2; ++qh) st[n][qh] = zero4;
#pragma unroll
        for (int n = 0; n < 4; ++n) {
            const int R = n * 16 + lo;
            bf16x8 k0 = *(const bf16x8*)&Kl[R * 64 + ((hi ^ l7) << 3)];
            bf16x8 k1 = *(const bf16x8*)&Kl[R * 64 + (((4 + hi) ^ l7) << 3)];
#pragma unroll
            for (int qh = 0; qh < 2; ++qh) {
                st[n][qh] = __builtin_amdgcn_mfma_f32_16x16x32_bf16(k0, qf[qh][0], st[n][qh], 0, 0, 0);
                st[n][qh] = __builtin_amdgcn_mfma_f32_16x16x32_bf16(k1, qf[qh][1], st[n][qh], 0, 0, 0);
            }
        }
        // V^T fragments for K=16 PV
        bf16x4 vf[4][4];
#pragma unroll
        for (int dt = 0; dt < 4; ++dt)
#pragma unroll
            for (int n = 0; n < 4; ++n)
                vf[dt][n] = *(const bf16x4*)&Vl[(dt * 16 + lo) * 64
                              + (((2 * n + (hi >> 1)) ^ l7) << 3) + ((hi & 1) << 2)];

        uint2 mw = *(const uint2*)&bits[b * 32 + tt * 2];

        // mask (scores already log2-scaled) + lane-local max
        f32x4 p[2][4];
        float mx[2];
        if ((mw.x | mw.y) == 0u) {  // fully valid tile: vectorized max tree, no mask math
#pragma unroll
            for (int qh = 0; qh < 2; ++qh) {
                f32x4 a = vmax4(vmax4(st[0][qh], st[1][qh]), vmax4(st[2][qh], st[3][qh]));
                mx[qh] = fmaxf(fmaxf(a[0], a[1]), fmaxf(a[2], a[3]));
#pragma unroll
                for (int n = 0; n < 4; ++n) p[qh][n] = st[n][qh];
            }
        } else {  // bitmask path (boundary tiles only)
            mx[0] = -1e30f; mx[1] = -1e30f;
#pragma unroll
            for (int n = 0; n < 4; ++n) {
                unsigned int wd = (n & 2) ? mw.y : mw.x;
#pragma unroll
                for (int r = 0; r < 4; ++r) {
                    int sh = ((n & 1) << 4) + (hi << 2) + r;
                    bool mk = (wd >> sh) & 1u;
#pragma unroll
                    for (int qh = 0; qh < 2; ++qh) {
                        float s = mk ? -1e30f : st[n][qh][r];
                        p[qh][n][r] = s;
                        mx[qh] = fmaxf(mx[qh], s);
                    }
                }
            }
        }
        float m2[2];
#pragma unroll
        for (int qh = 0; qh < 2; ++qh) {
            float v = fmaxf(mx[qh], __shfl_xor(mx[qh], 16));
            m2[qh] = fmaxf(v, __shfl_xor(v, 32));
        }
        // T13 defer-max: skip rescale while max growth <= 8 for every row in wave
        float growth = fmaxf(m2[0] - mrow[0], m2[1] - mrow[1]);
        if (!__all(growth <= 8.0f)) {
#pragma unroll
            for (int qh = 0; qh < 2; ++qh) {
                float mnew = fmaxf(mrow[qh], m2[qh]);
                float scl = __builtin_amdgcn_exp2f(mrow[qh] - mnew);
                mrow[qh] = mnew;
                lsum[qh] *= scl;
#pragma unroll
                for (int dt = 0; dt < 4; ++dt)
                    o[dt][qh] *= scl;
            }
        }
#pragma unroll
        for (int qh = 0; qh < 2; ++qh) {
            f32x4 rs4 = zero4;
#pragma unroll
            for (int n = 0; n < 4; ++n) {
                f32x4 e;
#pragma unroll
                for (int r = 0; r < 4; ++r)
                    e[r] = __builtin_amdgcn_exp2f(p[qh][n][r] - mrow[qh]);
                p[qh][n] = e;
                rs4 += e;
            }
            float rs = (rs4[0] + rs4[1]) + (rs4[2] + rs4[3]);
            rs += __shfl_xor(rs, 16);
            rs += __shfl_xor(rs, 32);
            lsum[qh] += rs;
        }
        // pack P^T (native bf16 casts -> compiler cvt_pk) and PV (K=16)
#pragma unroll
        for (int qh = 0; qh < 2; ++qh) {
#pragma unroll
            for (int n = 0; n < 4; ++n) {
                uint2 pk2;
                pk2.x = (unsigned int)f2bf(p[qh][n][0]) | ((unsigned int)f2bf(p[qh][n][1]) << 16);
                pk2.y = (unsigned int)f2bf(p[qh][n][2]) | ((unsigned int)f2bf(p[qh][n][3]) << 16);
                bf16x4 pb = __builtin_bit_cast(bf16x4, pk2);
#pragma unroll
                for (int dt = 0; dt < 4; ++dt)
                    o[dt][qh] = __builtin_amdgcn_mfma_f32_16x16x16bf16_1k(vf[dt][n], pb, o[dt][qh], 0, 0, 0);
            }
        }
        __syncthreads();  // drains stage vmcnt + all waves' LDS reads of buf[cur]
        cur ^= 1;
    }

    // epilogue: O^T -> O via wave-private LDS transpose
    unsigned short* Tl = &lds[w * 2304];  // [32][72]
    float inv[2] = {1.0f / lsum[0], 1.0f / lsum[1]};
#pragma unroll
    for (int qh = 0; qh < 2; ++qh)
#pragma unroll
        for (int dt = 0; dt < 4; ++dt)
#pragma unroll
            for (int r = 0; r < 4; ++r)
                Tl[(qh * 16 + lo) * 72 + dt * 16 + hi * 4 + r] = f2bf(o[dt][qh][r] * inv[qh]);
#pragma unroll
    for (int ps = 0; ps < 4; ++ps) {
        int row = ps * 8 + (lane >> 3);
        int col = (lane & 7) * 8;
        bf16x8 v = *(const bf16x8*)&Tl[row * 72 + col];
        *(bf16x8*)&Ob[(size_t)(b * S_ + qr0 + row) * DIM_ + h * 64 + col] = v;
    }
}

// ---------------- launch ----------------
extern "C" void kernel_launch(void* const* d_in, const int* in_sizes, int n_in,
                              void* d_out, int out_size, void* d_ws, size_t ws_size,
                              hipStream_t stream)
{
    const float* x  = (const float*)d_in[0];
    const float* cx = (const float*)d_in[1];
    const void* mask = d_in[2];
    const float* Wq = (const float*)d_in[3];
    const float* bq = (const float*)d_in[4];
    const float* Wk = (const float*)d_in[5];
    const float* bk = (const float*)d_in[6];
    const float* Wv = (const float*)d_in[7];
    const float* bv = (const float*)d_in[8];
    const float* Wo = (const float*)d_in[9];
    const float* bo = (const float*)d_in[10];

    unsigned short* ws = (unsigned short*)d_ws;
    const size_t XB  = 0;                                  // 8192*1024 (x bf16; later attn out)
    const size_t CXB = XB  + (size_t)8192 * 1024;          // 4096*768
    const size_t WQT = CXB + (size_t)4096 * 768;           // 1024*1024
    const size_t WKT = WQT + (size_t)1024 * 1024;          // 1024*768  \ contiguous = B^T(2048x768)
    const size_t WVT = WKT + (size_t)1024 * 768;           // 1024*768  /
    const size_t WOT = WVT + (size_t)1024 * 768;           // 1024*1024
    const size_t QB  = WOT + (size_t)1024 * 1024;          // 8192*1024
    const size_t KB  = QB  + (size_t)8192 * 1024;          // 4096*1024
    const size_t VTB = KB  + (size_t)4096 * 1024;          // 4*1024*1024
    const size_t MBT = VTB + (size_t)4 * 1024 * 1024;      // 128 uint32 = 256 ushort
    const size_t NTP = MBT + 256;                          // 4 ints

    k_f32_to_bf16<<<2048, 256, 0, stream>>>(x,  ws + XB,  8192 * 1024 / 4);
    k_f32_to_bf16<<<2048, 256, 0, stream>>>(cx, ws + CXB, 4096 * 768 / 4);
    k_transposeW4<<<1792, 256, 0, stream>>>(Wq, Wk, Wv, Wo, ws + WQT, ws + WKT, ws + WVT, ws + WOT);
    unsigned int* mbits = (unsigned int*)(ws + MBT);
    int* ntp = (int*)(ws + NTP);
    k_mask_bits<<<1, 256, 0, stream>>>((const unsigned int*)mask, mbits, ntp);

    const float QSCALE = 0.125f * 1.44269504088896340736f;  // 1/sqrt(64) * log2(e) folded into Q
    dim3 gq(8192 / 128, 1024 / 128);
    dim3 gkv(4096 / 128, 2048 / 128);
    k_gemm_bt<0><<<gq, 256, 0, stream>>>(ws + XB, ws + WQT, bq, nullptr, QSCALE, ws + QB, nullptr, nullptr, 8192, 1024, 1024);
    // merged K|V projection: K rows -> KB, V^T -> VTB
    k_gemm_bt<3><<<gkv, 256, 0, stream>>>(ws + CXB, ws + WKT, bk, bv, 1.0f, ws + KB, ws + VTB, nullptr, 4096, 2048, 768);

    dim3 ga(S_ / 128, NH_, B_);
    k_attn<<<ga, 256, 0, stream>>>(ws + QB, ws + KB, ws + VTB, mbits, ntp, ws + XB);

    k_gemm_bt<2><<<gq, 256, 0, stream>>>(ws + XB, ws + WOT, bo, nullptr, 1.0f, nullptr, nullptr, (float*)d_out, 8192, 1024, 1024);
}

// Round 11
// 153.794 us; speedup vs baseline: 1.4973x; 1.1100x over previous
//
#include <hip/hip_runtime.h>
#include <hip/hip_bf16.h>
#include <stdint.h>

#define DIM_ 1024
#define NH_ 16
#define HD_ 64
#define B_ 4
#define S_ 2048
#define SC_ 1024
#define CD_ 768

typedef __attribute__((ext_vector_type(8))) short bf16x8;
typedef __attribute__((ext_vector_type(4))) short bf16x4;
typedef __attribute__((ext_vector_type(4))) float f32x4;

// native bf16 cast (RTNE) -- compiler lowers pairs to v_cvt_pk_bf16_f32
__device__ inline unsigned short f2bf(float f) {
    __hip_bfloat16 h = __float2bfloat16(f);
    return __builtin_bit_cast(unsigned short, h);
}

__device__ inline f32x4 vmax4(f32x4 a, f32x4 b) {
    f32x4 r;
#pragma unroll
    for (int i = 0; i < 4; ++i) r[i] = fmaxf(a[i], b[i]);
    return r;
}

#define GLOAD16(SRC, DST) __builtin_amdgcn_global_load_lds( \
    (const __attribute__((address_space(1))) void*)(SRC),   \
    (__attribute__((address_space(3))) void*)(DST), 16, 0, 0)

// ---------------- fused conversion: x and cx -> bf16 in one launch ----------------
__global__ void k_f32_to_bf16_2(const float* __restrict__ in0, unsigned short* __restrict__ out0, int n40,
                                const float* __restrict__ in1, unsigned short* __restrict__ out1, int n41) {
    int i = blockIdx.x * blockDim.x + threadIdx.x;
    int stride = gridDim.x * blockDim.x;
    int total = n40 + n41;
    for (; i < total; i += stride) {
        const float4 v = (i < n40) ? ((const float4*)in0)[i] : ((const float4*)in1)[i - n40];
        uint2 pk;
        pk.x = (unsigned int)f2bf(v.x) | ((unsigned int)f2bf(v.y) << 16);
        pk.y = (unsigned int)f2bf(v.z) | ((unsigned int)f2bf(v.w) << 16);
        if (i < n40) ((uint2*)out0)[i] = pk;
        else         ((uint2*)out1)[i - n40] = pk;
    }
}

// All 4 weight transposes + mask-bits in one launch.
// Blocks 0..1791: W (K x 1024) -> WT (1024 x K) bf16, one 16B chunk per thread.
// Block 1792: per-batch key-padding bitmask + nt[b].
__global__ void k_transposeW4(const float* __restrict__ Wq, const float* __restrict__ Wk,
                              const float* __restrict__ Wv, const float* __restrict__ Wo,
                              unsigned short* __restrict__ WQT, unsigned short* __restrict__ WKT,
                              unsigned short* __restrict__ WVT, unsigned short* __restrict__ WOT,
                              const unsigned int* __restrict__ m,
                              unsigned int* __restrict__ bits, int* __restrict__ ntp) {
    if (blockIdx.x == 1792) {  // mask block
        __shared__ int bm_s;
        __shared__ unsigned int wbits[128];
        if (threadIdx.x == 0) bm_s = 0;
        __syncthreads();
        int any = 0;
        for (int i = threadIdx.x; i < 1024; i += 256)  // first 4096 bytes: safe both modes
            if (m[i] > 1u) any = 1;
        if (any) atomicOr(&bm_s, 1);
        __syncthreads();
        const int boolmode = bm_s;
        const int w = threadIdx.x;
        if (w < 128) {
            const unsigned char* mb = (const unsigned char*)m;
            unsigned int out = 0;
            for (int j = 0; j < 32; ++j) {
                int c = w * 32 + j;
                int masked = boolmode ? (mb[c] != 0) : (m[c] != 0u);
                out |= (unsigned int)masked << j;
            }
            bits[w] = out;
            wbits[w] = out;
        }
        __syncthreads();
        if (threadIdx.x < 4) {
            int nt = 0;
            for (int tt = 0; tt < 16; ++tt) {
                unsigned int w0 = wbits[threadIdx.x * 32 + tt * 2];
                unsigned int w1 = wbits[threadIdx.x * 32 + tt * 2 + 1];
                if ((w0 & w1) != 0xFFFFFFFFu) nt = tt + 1;  // tile has >=1 valid key
            }
            ntp[threadIdx.x] = nt;
        }
        return;
    }
    int idx = blockIdx.x * blockDim.x + threadIdx.x;
    const float* W; unsigned short* WT; int K;
    if (idx < 131072)      { W = Wq; WT = WQT; K = 1024; }
    else if (idx < 229376) { W = Wk; WT = WKT; K = 768;  idx -= 131072; }
    else if (idx < 327680) { W = Wv; WT = WVT; K = 768;  idx -= 229376; }
    else                   { W = Wo; WT = WOT; K = 1024; idx -= 327680; }
    int n = idx & 1023;
    int k0 = (idx >> 10) << 3;
    unsigned int pk[4];
#pragma unroll
    for (int j = 0; j < 4; ++j) {
        unsigned short a = f2bf(W[(size_t)(k0 + 2 * j) * 1024 + n]);
        unsigned short b = f2bf(W[(size_t)(k0 + 2 * j + 1) * 1024 + n]);
        pk[j] = (unsigned int)a | ((unsigned int)b << 16);
    }
    *(uint4*)&WT[(size_t)n * K + k0] = *(uint4*)pk;
}

// ---------------- bf16 GEMM: BK=64, XOR-swizzled LDS, double-buffered, one barrier/step ----
// Staging and fragment-read geometry identical to k_attn's proven K-tile path:
// global source pre-swizzled (block (l&7)^srow), ds_read applies block^(row&7).
// C = (A * BT^T + bias) * oscale. T1 XCD-swizzle. Accumulation order identical
// to BK=32 version (kk=0 then kk=1) -> bit-identical results.
// EPI 0: bf16 row-major. EPI 2: f32 row-major. EPI 3: merged K|V.
template<int EPI>
__global__ __launch_bounds__(256) void k_gemm_bt(
    const unsigned short* __restrict__ A, const unsigned short* __restrict__ BT,
    const float* __restrict__ bias, const float* __restrict__ bias2, float oscale,
    unsigned short* __restrict__ Cb, unsigned short* __restrict__ Cb2,
    float* __restrict__ Cf, int M, int N, int K)
{
    __shared__ unsigned short As[2][128 * 64];
    __shared__ unsigned short Bs[2][128 * 64];
    const int t = threadIdx.x;
    const int w = t >> 6, lane = t & 63;
    const int lo = lane & 15, hi = lane >> 4;
    const int l7 = lo & 7;
    const int nwg = gridDim.x * gridDim.y;
    const int wg = blockIdx.y * gridDim.x + blockIdx.x;
    const int swz = (wg & 7) * (nwg >> 3) + (wg >> 3);
    const int m0 = (swz % gridDim.x) * 128, n0 = (swz / gridDim.x) * 128;
    const int wr = (w >> 1) * 64, wc = (w & 1) * 64;
    const int srow = lane >> 3;                 // 0..7 within an 8-row pass
    const int scb  = ((lane & 7) ^ srow) << 3;  // pre-swizzled source 16B block

    f32x4 zero4 = {0.f, 0.f, 0.f, 0.f};
    f32x4 acc[4][4];
    for (int i = 0; i < 4; ++i)
        for (int j = 0; j < 4; ++j) acc[i][j] = zero4;

    // prologue: stage K-slice 0 into buf 0 (4 passes x 8 rows per wave, per matrix)
#pragma unroll
    for (int p = 0; p < 4; ++p) {
        int rb = w * 32 + p * 8;
        GLOAD16(&A[(size_t)(m0 + rb + srow) * K + scb], &As[0][rb * 64]);
        GLOAD16(&BT[(size_t)(n0 + rb + srow) * K + scb], &Bs[0][rb * 64]);
    }
    __syncthreads();

    int cur = 0;
    for (int k0 = 0; k0 < K; k0 += 64) {
        if (k0 + 64 < K) {  // stage next slice; lands at this iter's barrier drain
#pragma unroll
            for (int p = 0; p < 4; ++p) {
                int rb = w * 32 + p * 8;
                GLOAD16(&A[(size_t)(m0 + rb + srow) * K + k0 + 64 + scb], &As[cur ^ 1][rb * 64]);
                GLOAD16(&BT[(size_t)(n0 + rb + srow) * K + k0 + 64 + scb], &Bs[cur ^ 1][rb * 64]);
            }
        }
#pragma unroll
        for (int kk = 0; kk < 2; ++kk) {
            bf16x8 af[4], bfr[4];
#pragma unroll
            for (int i = 0; i < 4; ++i) {
                int row = wr + i * 16 + lo;  // row&7 == l7
                af[i] = *(const bf16x8*)&As[cur][row * 64 + ((((kk << 2) + hi) ^ l7) << 3)];
            }
#pragma unroll
            for (int j = 0; j < 4; ++j) {
                int row = wc + j * 16 + lo;
                bfr[j] = *(const bf16x8*)&Bs[cur][row * 64 + ((((kk << 2) + hi) ^ l7) << 3)];
            }
#pragma unroll
            for (int i = 0; i < 4; ++i)
#pragma unroll
                for (int j = 0; j < 4; ++j)
                    acc[i][j] = __builtin_amdgcn_mfma_f32_16x16x32_bf16(af[i], bfr[j], acc[i][j], 0, 0, 0);
        }
        __syncthreads();  // reads of buf[cur] done; staged buf[cur^1] landed (vmcnt drain)
        cur ^= 1;
    }

#pragma unroll
    for (int i = 0; i < 4; ++i) {
#pragma unroll
        for (int j = 0; j < 4; ++j) {
            int n = n0 + wc + j * 16 + lo;
            int mbase = m0 + wr + i * 16 + (hi << 2);
            if (EPI == 3 && n >= 1024) {
                // V^T half: lane holds 4 consecutive c (= mbase+r) for column d.
                float b2 = bias2[n - 1024];
                uint2 pk;
                pk.x = (unsigned int)f2bf(acc[i][j][0] + b2) | ((unsigned int)f2bf(acc[i][j][1] + b2) << 16);
                pk.y = (unsigned int)f2bf(acc[i][j][2] + b2) | ((unsigned int)f2bf(acc[i][j][3] + b2) << 16);
                int bb = mbase >> 10, c = mbase & 1023;
                *(uint2*)&Cb2[(size_t)((bb << 10) + (n - 1024)) * 1024 + c] = pk;
            } else {
#pragma unroll
                for (int r = 0; r < 4; ++r) {
                    int m = mbase + r;
                    if (EPI == 0) {
                        float v = (acc[i][j][r] + bias[n]) * oscale;
                        Cb[(size_t)m * 1024 + n] = f2bf(v);
                    } else if (EPI == 2) {
                        float v = (acc[i][j][r] + bias[n]) * oscale;
                        Cf[(size_t)m * 1024 + n] = v;
                    } else {  // EPI 3, K half
                        float v = acc[i][j][r] + bias[n];
                        Cb[(size_t)m * 1024 + n] = f2bf(v);
                    }
                }
            }
        }
    }
}

// ---------------- fused flash attention (unchanged from round 10) ----------------
__global__ __launch_bounds__(256) void k_attn(
    const unsigned short* __restrict__ Q, const unsigned short* __restrict__ Kb,
    const unsigned short* __restrict__ VT, const unsigned int* __restrict__ bits,
    const int* __restrict__ ntp, unsigned short* __restrict__ Ob)
{
    __shared__ unsigned short lds[16384];  // K0|K1|V0|V1, 4096 ushorts (64x64) each
    const int t = threadIdx.x, w = t >> 6, lane = t & 63;
    const int lo = lane & 15, hi = lane >> 4;
    const int qt = blockIdx.x, h = blockIdx.y, b = blockIdx.z;
    const int qr0 = qt * 128 + w * 32;
    const int l7 = lo & 7;
    const int nt = ntp[b];

    const int srow = lane >> 3;
    const int scb  = ((lane & 7) ^ srow) << 3;

    bf16x8 qf[2][2];
#pragma unroll
    for (int qh = 0; qh < 2; ++qh)
#pragma unroll
        for (int kk = 0; kk < 2; ++kk)
            qf[qh][kk] = *(const bf16x8*)&Q[(size_t)(b * S_ + qr0 + qh * 16 + lo) * DIM_ + h * 64 + kk * 32 + hi * 8];

    f32x4 zero4 = {0.f, 0.f, 0.f, 0.f};
    float mrow[2] = {-1e30f, -1e30f}, lsum[2] = {0.f, 0.f};
    f32x4 o[4][2];
#pragma unroll
    for (int dt = 0; dt < 4; ++dt)
#pragma unroll
        for (int qh = 0; qh < 2; ++qh) o[dt][qh] = zero4;

    // prologue: stage tile 0 into buf 0
#pragma unroll
    for (int s = 0; s < 2; ++s) {
        int rl = w * 16 + s * 8 + srow;
        GLOAD16(&Kb[(size_t)(b * SC_ + rl) * DIM_ + h * 64 + scb], &lds[(w * 16 + s * 8) * 64]);
        GLOAD16(&VT[(size_t)(b * 1024 + h * 64 + rl) * SC_ + scb], &lds[8192 + (w * 16 + s * 8) * 64]);
    }
    __syncthreads();

    int cur = 0;
    for (int tt = 0; tt < nt; ++tt) {
        if (tt + 1 < nt) {
            int c0n = (tt + 1) * 64;
#pragma unroll
            for (int s = 0; s < 2; ++s) {
                int rl = w * 16 + s * 8 + srow;
                GLOAD16(&Kb[(size_t)(b * SC_ + c0n + rl) * DIM_ + h * 64 + scb],
                        &lds[(cur ^ 1) * 4096 + (w * 16 + s * 8) * 64]);
                GLOAD16(&VT[(size_t)(b * 1024 + h * 64 + rl) * SC_ + c0n + scb],
                        &lds[8192 + (cur ^ 1) * 4096 + (w * 16 + s * 8) * 64]);
            }
        }
        const unsigned short* Kl = &lds[cur * 4096];
        const unsigned short* Vl = &lds[8192 + cur * 4096];

        f32x4 st[4][2];
#pragma unroll
        for (int n = 0; n < 4; ++n)
#pragma unroll
            for (int qh = 0; qh < 2; ++qh) st[n][qh] = zero4;
#pragma unroll
        for (int n = 0; n < 4; ++n) {
            const int R = n * 16 + lo;
            bf16x8 k0 = *(const bf16x8*)&Kl[R * 64 + ((hi ^ l7) << 3)];
            bf16x8 k1 = *(const bf16x8*)&Kl[R * 64 + (((4 + hi) ^ l7) << 3)];
#pragma unroll
            for (int qh = 0; qh < 2; ++qh) {
                st[n][qh] = __builtin_amdgcn_mfma_f32_16x16x32_bf16(k0, qf[qh][0], st[n][qh], 0, 0, 0);
                st[n][qh] = __builtin_amdgcn_mfma_f32_16x16x32_bf16(k1, qf[qh][1], st[n][qh], 0, 0, 0);
            }
        }
        bf16x4 vf[4][4];
#pragma unroll
        for (int dt = 0; dt < 4; ++dt)
#pragma unroll
            for (int n = 0; n < 4; ++n)
                vf[dt][n] = *(const bf16x4*)&Vl[(dt * 16 + lo) * 64
                              + (((2 * n + (hi >> 1)) ^ l7) << 3) + ((hi & 1) << 2)];

        uint2 mw = *(const uint2*)&bits[b * 32 + tt * 2];

        f32x4 p[2][4];
        float mx[2];
        if ((mw.x | mw.y) == 0u) {
#pragma unroll
            for (int qh = 0; qh < 2; ++qh) {
                f32x4 a = vmax4(vmax4(st[0][qh], st[1][qh]), vmax4(st[2][qh], st[3][qh]));
                mx[qh] = fmaxf(fmaxf(a[0], a[1]), fmaxf(a[2], a[3]));
#pragma unroll
                for (int n = 0; n < 4; ++n) p[qh][n] = st[n][qh];
            }
        } else {
            mx[0] = -1e30f; mx[1] = -1e30f;
#pragma unroll
            for (int n = 0; n < 4; ++n) {
                unsigned int wd = (n & 2) ? mw.y : mw.x;
#pragma unroll
                for (int r = 0; r < 4; ++r) {
                    int sh = ((n & 1) << 4) + (hi << 2) + r;
                    bool mk = (wd >> sh) & 1u;
#pragma unroll
                    for (int qh = 0; qh < 2; ++qh) {
                        float s = mk ? -1e30f : st[n][qh][r];
                        p[qh][n][r] = s;
                        mx[qh] = fmaxf(mx[qh], s);
                    }
                }
            }
        }
        float m2[2];
#pragma unroll
        for (int qh = 0; qh < 2; ++qh) {
            float v = fmaxf(mx[qh], __shfl_xor(mx[qh], 16));
            m2[qh] = fmaxf(v, __shfl_xor(v, 32));
        }
        float growth = fmaxf(m2[0] - mrow[0], m2[1] - mrow[1]);
        if (!__all(growth <= 8.0f)) {
#pragma unroll
            for (int qh = 0; qh < 2; ++qh) {
                float mnew = fmaxf(mrow[qh], m2[qh]);
                float scl = __builtin_amdgcn_exp2f(mrow[qh] - mnew);
                mrow[qh] = mnew;
                lsum[qh] *= scl;
#pragma unroll
                for (int dt = 0; dt < 4; ++dt)
                    o[dt][qh] *= scl;
            }
        }
#pragma unroll
        for (int qh = 0; qh < 2; ++qh) {
            f32x4 rs4 = zero4;
#pragma unroll
            for (int n = 0; n < 4; ++n) {
                f32x4 e;
#pragma unroll
                for (int r = 0; r < 4; ++r)
                    e[r] = __builtin_amdgcn_exp2f(p[qh][n][r] - mrow[qh]);
                p[qh][n] = e;
                rs4 += e;
            }
            float rs = (rs4[0] + rs4[1]) + (rs4[2] + rs4[3]);
            rs += __shfl_xor(rs, 16);
            rs += __shfl_xor(rs, 32);
            lsum[qh] += rs;
        }
#pragma unroll
        for (int qh = 0; qh < 2; ++qh) {
#pragma unroll
            for (int n = 0; n < 4; ++n) {
                uint2 pk2;
                pk2.x = (unsigned int)f2bf(p[qh][n][0]) | ((unsigned int)f2bf(p[qh][n][1]) << 16);
                pk2.y = (unsigned int)f2bf(p[qh][n][2]) | ((unsigned int)f2bf(p[qh][n][3]) << 16);
                bf16x4 pb = __builtin_bit_cast(bf16x4, pk2);
#pragma unroll
                for (int dt = 0; dt < 4; ++dt)
                    o[dt][qh] = __builtin_amdgcn_mfma_f32_16x16x16bf16_1k(vf[dt][n], pb, o[dt][qh], 0, 0, 0);
            }
        }
        __syncthreads();
        cur ^= 1;
    }

    unsigned short* Tl = &lds[w * 2304];  // [32][72]
    float inv[2] = {1.0f / lsum[0], 1.0f / lsum[1]};
#pragma unroll
    for (int qh = 0; qh < 2; ++qh)
#pragma unroll
        for (int dt = 0; dt < 4; ++dt)
#pragma unroll
            for (int r = 0; r < 4; ++r)
                Tl[(qh * 16 + lo) * 72 + dt * 16 + hi * 4 + r] = f2bf(o[dt][qh][r] * inv[qh]);
#pragma unroll
    for (int ps = 0; ps < 4; ++ps) {
        int row = ps * 8 + (lane >> 3);
        int col = (lane & 7) * 8;
        bf16x8 v = *(const bf16x8*)&Tl[row * 72 + col];
        *(bf16x8*)&Ob[(size_t)(b * S_ + qr0 + row) * DIM_ + h * 64 + col] = v;
    }
}

// ---------------- launch ----------------
extern "C" void kernel_launch(void* const* d_in, const int* in_sizes, int n_in,
                              void* d_out, int out_size, void* d_ws, size_t ws_size,
                              hipStream_t stream)
{
    const float* x  = (const float*)d_in[0];
    const float* cx = (const float*)d_in[1];
    const void* mask = d_in[2];
    const float* Wq = (const float*)d_in[3];
    const float* bq = (const float*)d_in[4];
    const float* Wk = (const float*)d_in[5];
    const float* bk = (const float*)d_in[6];
    const float* Wv = (const float*)d_in[7];
    const float* bv = (const float*)d_in[8];
    const float* Wo = (const float*)d_in[9];
    const float* bo = (const float*)d_in[10];

    unsigned short* ws = (unsigned short*)d_ws;
    const size_t XB  = 0;                                  // 8192*1024 (x bf16; later attn out)
    const size_t CXB = XB  + (size_t)8192 * 1024;          // 4096*768
    const size_t WQT = CXB + (size_t)4096 * 768;           // 1024*1024
    const size_t WKT = WQT + (size_t)1024 * 1024;          // 1024*768  \ contiguous = B^T(2048x768)
    const size_t WVT = WKT + (size_t)1024 * 768;           // 1024*768  /
    const size_t WOT = WVT + (size_t)1024 * 768;           // 1024*1024
    const size_t QB  = WOT + (size_t)1024 * 1024;          // 8192*1024
    const size_t KB  = QB  + (size_t)8192 * 1024;          // 4096*1024
    const size_t VTB = KB  + (size_t)4096 * 1024;          // 4*1024*1024
    const size_t MBT = VTB + (size_t)4 * 1024 * 1024;      // 128 uint32 = 256 ushort
    const size_t NTP = MBT + 256;                          // 4 ints

    unsigned int* mbits = (unsigned int*)(ws + MBT);
    int* ntp = (int*)(ws + NTP);

    k_f32_to_bf16_2<<<2048, 256, 0, stream>>>(x, ws + XB, 8192 * 1024 / 4,
                                              cx, ws + CXB, 4096 * 768 / 4);
    k_transposeW4<<<1793, 256, 0, stream>>>(Wq, Wk, Wv, Wo,
                                            ws + WQT, ws + WKT, ws + WVT, ws + WOT,
                                            (const unsigned int*)mask, mbits, ntp);

    const float QSCALE = 0.125f * 1.44269504088896340736f;  // 1/sqrt(64) * log2(e) folded into Q
    dim3 gq(8192 / 128, 1024 / 128);
    dim3 gkv(4096 / 128, 2048 / 128);
    k_gemm_bt<0><<<gq, 256, 0, stream>>>(ws + XB, ws + WQT, bq, nullptr, QSCALE, ws + QB, nullptr, nullptr, 8192, 1024, 1024);
    // merged K|V projection: K rows -> KB, V^T -> VTB
    k_gemm_bt<3><<<gkv, 256, 0, stream>>>(ws + CXB, ws + WKT, bk, bv, 1.0f, ws + KB, ws + VTB, nullptr, 4096, 2048, 768);

    dim3 ga(S_ / 128, NH_, B_);
    k_attn<<<ga, 256, 0, stream>>>(ws + QB, ws + KB, ws + VTB, mbits, ntp, ws + XB);

    k_gemm_bt<2><<<gq, 256, 0, stream>>>(ws + XB, ws + WOT, bo, nullptr, 1.0f, nullptr, nullptr, (float*)d_out, 8192, 1024, 1024);
}